// Round 1
// baseline (236.052 us; speedup 1.0000x reference)
//
#include <hip/hip_runtime.h>

#define NB 4
#define SEQ 4096
#define EMB 768
#define AD 64
#define BS (NB*SEQ)

typedef short short8 __attribute__((ext_vector_type(8)));
typedef float f32x4 __attribute__((ext_vector_type(4)));
typedef unsigned short u16;

__device__ __forceinline__ u16 f2bf(float f) {
  union { float f; unsigned u; } v; v.f = f;
  unsigned u = v.u;
  unsigned r = (u + 0x7FFFu + ((u >> 16) & 1u)) >> 16;  // RNE
  return (u16)r;
}

__device__ __forceinline__ f32x4 mfma16(short8 a, short8 b, f32x4 c) {
  return __builtin_amdgcn_mfma_f32_16x16x32_bf16(a, b, c, 0, 0, 0);
}

// ---------------- Kernel 0: weight transpose + bf16 cast --------------------
// Wt[(m*64 + col)*768 + e] = W_m[e*64 + col], m in {q,k,v}
__global__ void wt_kernel(const float* __restrict__ Wq, const float* __restrict__ Wk,
                          const float* __restrict__ Wv, u16* __restrict__ Wt) {
  int idx = blockIdx.x * 256 + threadIdx.x;
  if (idx >= 3 * AD * EMB) return;
  int m   = idx / (AD * EMB);
  int rem = idx - m * (AD * EMB);
  int col = rem / EMB;
  int e   = rem - col * EMB;
  const float* W = (m == 0) ? Wq : (m == 1) ? Wk : Wv;
  Wt[idx] = f2bf(W[e * AD + col]);
}

// ---------------- Kernel 1: fused QKV projection (bf16 MFMA) ----------------
// grid = BS/64 blocks, 256 threads (4 waves x 16 rows).
__global__ __launch_bounds__(256) void proj_kernel(const float* __restrict__ emb,
                                                   const u16* __restrict__ Wt,
                                                   u16* __restrict__ Q, u16* __restrict__ K,
                                                   u16* __restrict__ V) {
  const int w = threadIdx.x >> 6;
  const int lane = threadIdx.x & 63;
  const int g = lane >> 4, c = lane & 15;
  const int rbase = blockIdx.x * 64 + w * 16;

  f32x4 aq[4], ak[4], av[4];
#pragma unroll
  for (int cf = 0; cf < 4; cf++)
#pragma unroll
    for (int r = 0; r < 4; r++) { aq[cf][r] = 0.f; ak[cf][r] = 0.f; av[cf][r] = 0.f; }

  const float* arow = emb + (size_t)(rbase + c) * EMB;

  for (int e0 = 0; e0 < EMB; e0 += 32) {
    float4 x0 = *(const float4*)(arow + e0 + g * 8);
    float4 x1 = *(const float4*)(arow + e0 + g * 8 + 4);
    short8 af;
    af[0] = (short)f2bf(x0.x); af[1] = (short)f2bf(x0.y);
    af[2] = (short)f2bf(x0.z); af[3] = (short)f2bf(x0.w);
    af[4] = (short)f2bf(x1.x); af[5] = (short)f2bf(x1.y);
    af[6] = (short)f2bf(x1.z); af[7] = (short)f2bf(x1.w);
#pragma unroll
    for (int cf = 0; cf < 4; cf++) {
      const u16* wp = Wt + (size_t)(cf * 16 + c) * EMB + e0 + g * 8;
      short8 bq = *(const short8*)(wp);
      short8 bk = *(const short8*)(wp + AD * EMB);
      short8 bv = *(const short8*)(wp + 2 * AD * EMB);
      aq[cf] = mfma16(af, bq, aq[cf]);
      ak[cf] = mfma16(af, bk, ak[cf]);
      av[cf] = mfma16(af, bv, av[cf]);
    }
  }

#pragma unroll
  for (int cf = 0; cf < 4; cf++) {
#pragma unroll
    for (int r = 0; r < 4; r++) {
      const size_t row = (size_t)(rbase + g * 4 + r);
      const int col = cf * 16 + c;
      Q[row * AD + col] = f2bf(aq[cf][r] * 0.125f);  // fold 1/sqrt(64) into Q
      K[row * AD + col] = f2bf(ak[cf][r]);
      V[row * AD + col] = f2bf(av[cf][r]);
    }
  }
}

// ---------------- Kernel 2: V transpose  [b][s][d] -> [b][d][s] -------------
__global__ __launch_bounds__(256) void transv_kernel(const u16* __restrict__ V,
                                                     u16* __restrict__ Vt) {
  const int b = blockIdx.y;
  const int sb = blockIdx.x * 64;
  __shared__ u16 t[64][65];
#pragma unroll
  for (int it = 0; it < 16; ++it) {
    int s = it * 4 + (threadIdx.x >> 6);
    int d = threadIdx.x & 63;
    t[s][d] = V[((size_t)b * SEQ + sb + s) * AD + d];
  }
  __syncthreads();
#pragma unroll
  for (int it = 0; it < 16; ++it) {
    int d = it * 4 + (threadIdx.x >> 6);
    int s = threadIdx.x & 63;
    Vt[(size_t)(b * AD + d) * SEQ + sb + s] = t[s][d];
  }
}

// ---------------- Kernel 3: causal flash attention ---------------------------
// grid (SEQ/64, NB), 256 threads = 4 waves; wave owns 16 q-rows, KVBLK = 64.
__global__ __launch_bounds__(256) void flash_kernel(const u16* __restrict__ Q,
                                                    const u16* __restrict__ K,
                                                    const u16* __restrict__ Vt,
                                                    float* __restrict__ out) {
  const int bx = blockIdx.x;
  const int b  = blockIdx.y;
  const int w = threadIdx.x >> 6;
  const int lane = threadIdx.x & 63;
  const int g = lane >> 4, c = lane & 15;
  const int qw = bx * 64 + w * 16;

  const u16* Qb = Q + (size_t)b * SEQ * AD;
  const u16* Kb = K + (size_t)b * SEQ * AD;
  const u16* Vb = Vt + (size_t)b * AD * SEQ;

  __shared__ __align__(16) u16 plds_all[4][16 * 64];
  u16* plds = plds_all[w];

  const short8 qf0 = *(const short8*)(Qb + (size_t)(qw + c) * AD + g * 8);
  const short8 qf1 = *(const short8*)(Qb + (size_t)(qw + c) * AD + 32 + g * 8);

  float mrow[4], lrow[4];
  f32x4 o[4];
#pragma unroll
  for (int r = 0; r < 4; r++) { mrow[r] = -INFINITY; lrow[r] = 0.f; }
#pragma unroll
  for (int cf = 0; cf < 4; cf++)
#pragma unroll
    for (int r = 0; r < 4; r++) o[cf][r] = 0.f;

  const int ntiles = bx + 1;
  for (int kt = 0; kt < ntiles; ++kt) {
    const int kv0 = kt * 64;
    f32x4 s4[4];
#pragma unroll
    for (int cf = 0; cf < 4; cf++)
#pragma unroll
      for (int r = 0; r < 4; r++) s4[cf][r] = 0.f;

    // ---- QK^T: A = Q rows (row = c), B = K rows (col = c), k = d ----
#pragma unroll
    for (int cf = 0; cf < 4; cf++) {
      const u16* kp = Kb + (size_t)(kv0 + cf * 16 + c) * AD + g * 8;
      short8 k0 = *(const short8*)(kp);
      short8 k1 = *(const short8*)(kp + 32);
      s4[cf] = mfma16(qf0, k0, s4[cf]);
      s4[cf] = mfma16(qf1, k1, s4[cf]);
    }

    // ---- causal mask (diagonal tile only) + tile row-max ----
    float mt[4];
#pragma unroll
    for (int r = 0; r < 4; r++) mt[r] = -INFINITY;
    if (kt == ntiles - 1) {
#pragma unroll
      for (int cf = 0; cf < 4; cf++) {
        const int kvg = kv0 + cf * 16 + c;
#pragma unroll
        for (int r = 0; r < 4; r++) {
          float v = s4[cf][r];
          v = (kvg <= qw + g * 4 + r) ? v : -INFINITY;
          s4[cf][r] = v;
          mt[r] = fmaxf(mt[r], v);
        }
      }
    } else {
#pragma unroll
      for (int cf = 0; cf < 4; cf++)
#pragma unroll
        for (int r = 0; r < 4; r++) mt[r] = fmaxf(mt[r], s4[cf][r]);
    }
    // reduce across the 16 lanes of the lane-group (they share q-rows)
#pragma unroll
    for (int r = 0; r < 4; r++) {
      mt[r] = fmaxf(mt[r], __shfl_xor(mt[r], 1));
      mt[r] = fmaxf(mt[r], __shfl_xor(mt[r], 2));
      mt[r] = fmaxf(mt[r], __shfl_xor(mt[r], 4));
      mt[r] = fmaxf(mt[r], __shfl_xor(mt[r], 8));
    }

    float corr[4];
#pragma unroll
    for (int r = 0; r < 4; r++) {
      float mn = fmaxf(mrow[r], mt[r]);
      corr[r] = __expf(mrow[r] - mn);  // exp(-inf)=0 on first tile
      mrow[r] = mn;
    }

    // ---- P = exp(S - m), row-sum, bf16 -> swizzled LDS ----
    float rs[4] = {0.f, 0.f, 0.f, 0.f};
#pragma unroll
    for (int cf = 0; cf < 4; cf++) {
#pragma unroll
      for (int r = 0; r < 4; r++) {
        float p = __expf(s4[cf][r] - mrow[r]);
        rs[r] += p;
        const int row = g * 4 + r;
        const int col = cf * 16 + c;
        const int phys = (row << 6) | ((((col >> 3) ^ row) & 7) << 3) | (col & 7);
        plds[phys] = f2bf(p);
      }
    }
#pragma unroll
    for (int r = 0; r < 4; r++) {
      rs[r] += __shfl_xor(rs[r], 1);
      rs[r] += __shfl_xor(rs[r], 2);
      rs[r] += __shfl_xor(rs[r], 4);
      rs[r] += __shfl_xor(rs[r], 8);
      lrow[r] = lrow[r] * corr[r] + rs[r];
    }
#pragma unroll
    for (int cf = 0; cf < 4; cf++) {
      o[cf][0] *= corr[0]; o[cf][1] *= corr[1];
      o[cf][2] *= corr[2]; o[cf][3] *= corr[3];
    }

    asm volatile("s_waitcnt lgkmcnt(0)" ::: "memory");

    // ---- PV: A = P (row = c = q, k = kv), B = Vt rows (col = c = d) ----
#pragma unroll
    for (int ks = 0; ks < 2; ++ks) {
      const int oct = ks * 4 + g;
      const short8 pf = *(const short8*)(plds + (c << 6) + (((oct ^ c) & 7) << 3));
#pragma unroll
      for (int cf = 0; cf < 4; cf++) {
        const short8 vf = *(const short8*)(Vb + (size_t)(cf * 16 + c) * SEQ + kv0 + ks * 32 + g * 8);
        o[cf] = mfma16(pf, vf, o[cf]);
      }
    }
  }

  // ---- epilogue: O / l, round to 4 decimals, store fp32 ----
  float rinv[4];
#pragma unroll
  for (int r = 0; r < 4; r++) rinv[r] = 1.0f / lrow[r];
#pragma unroll
  for (int cf = 0; cf < 4; cf++) {
#pragma unroll
    for (int r = 0; r < 4; r++) {
      float v = o[cf][r] * rinv[r];
      v = rintf(v * 1.0e4f) * 1.0e-4f;
      out[((size_t)b * SEQ + qw + g * 4 + r) * AD + cf * 16 + c] = v;
    }
  }
}

extern "C" void kernel_launch(void* const* d_in, const int* in_sizes, int n_in,
                              void* d_out, int out_size, void* d_ws, size_t ws_size,
                              hipStream_t stream) {
  const float* emb = (const float*)d_in[0];
  const float* Wq  = (const float*)d_in[1];
  const float* Wk  = (const float*)d_in[2];
  const float* Wv  = (const float*)d_in[3];
  float* out = (float*)d_out;

  char* ws = (char*)d_ws;
  u16* Wt = (u16*)ws;                         // 3*64*768*2      = 294912 B
  u16* Q  = (u16*)(ws + 294912);              // BS*64*2         = 2 MiB
  u16* K  = Q + (size_t)BS * AD;
  u16* V  = K + (size_t)BS * AD;
  u16* Vt = V + (size_t)BS * AD;              // total ~8.7 MiB

  wt_kernel<<<(3 * AD * EMB + 255) / 256, 256, 0, stream>>>(Wq, Wk, Wv, Wt);
  proj_kernel<<<BS / 64, 256, 0, stream>>>(emb, Wt, Q, K, V);
  transv_kernel<<<dim3(SEQ / 64, NB), 256, 0, stream>>>(V, Vt);
  flash_kernel<<<dim3(SEQ / 64, NB), 256, 0, stream>>>(Q, K, Vt, out);
}

// Round 2
// 149.660 us; speedup vs baseline: 1.5772x; 1.5772x over previous
//
#include <hip/hip_runtime.h>

#define NB 4
#define SEQ 4096
#define EMB 768
#define AD 64
#define BS (NB*SEQ)
#define CHK 16   // kv tiles (of 64) per chunk

typedef short short8 __attribute__((ext_vector_type(8)));
typedef float f32x4 __attribute__((ext_vector_type(4)));
typedef unsigned short u16;

__device__ __forceinline__ u16 f2bf(float f) {
  union { float f; unsigned u; } v; v.f = f;
  unsigned u = v.u;
  unsigned r = (u + 0x7FFFu + ((u >> 16) & 1u)) >> 16;  // RNE
  return (u16)r;
}

__device__ __forceinline__ f32x4 mfma16(short8 a, short8 b, f32x4 c) {
  return __builtin_amdgcn_mfma_f32_16x16x32_bf16(a, b, c, 0, 0, 0);
}

// ---------------- Kernel 0: weight transpose + bf16 cast --------------------
__global__ void wt_kernel(const float* __restrict__ Wq, const float* __restrict__ Wk,
                          const float* __restrict__ Wv, u16* __restrict__ Wt) {
  int idx = blockIdx.x * 256 + threadIdx.x;
  if (idx >= 3 * AD * EMB) return;
  int m   = idx / (AD * EMB);
  int rem = idx - m * (AD * EMB);
  int col = rem / EMB;
  int e   = rem - col * EMB;
  const float* W = (m == 0) ? Wq : (m == 1) ? Wk : Wv;
  Wt[idx] = f2bf(W[e * AD + col]);
}

// ---------------- Kernel 1: fused QKV projection (bf16 MFMA) ----------------
__global__ __launch_bounds__(256) void proj_kernel(const float* __restrict__ emb,
                                                   const u16* __restrict__ Wt,
                                                   u16* __restrict__ Q, u16* __restrict__ K,
                                                   u16* __restrict__ V) {
  const int w = threadIdx.x >> 6;
  const int lane = threadIdx.x & 63;
  const int g = lane >> 4, c = lane & 15;
  const int rbase = blockIdx.x * 64 + w * 16;

  f32x4 aq[4], ak[4], av[4];
#pragma unroll
  for (int cf = 0; cf < 4; cf++)
#pragma unroll
    for (int r = 0; r < 4; r++) { aq[cf][r] = 0.f; ak[cf][r] = 0.f; av[cf][r] = 0.f; }

  const float* arow = emb + (size_t)(rbase + c) * EMB;

  for (int e0 = 0; e0 < EMB; e0 += 32) {
    float4 x0 = *(const float4*)(arow + e0 + g * 8);
    float4 x1 = *(const float4*)(arow + e0 + g * 8 + 4);
    short8 af;
    af[0] = (short)f2bf(x0.x); af[1] = (short)f2bf(x0.y);
    af[2] = (short)f2bf(x0.z); af[3] = (short)f2bf(x0.w);
    af[4] = (short)f2bf(x1.x); af[5] = (short)f2bf(x1.y);
    af[6] = (short)f2bf(x1.z); af[7] = (short)f2bf(x1.w);
#pragma unroll
    for (int cf = 0; cf < 4; cf++) {
      const u16* wp = Wt + (size_t)(cf * 16 + c) * EMB + e0 + g * 8;
      short8 bq = *(const short8*)(wp);
      short8 bk = *(const short8*)(wp + AD * EMB);
      short8 bv = *(const short8*)(wp + 2 * AD * EMB);
      aq[cf] = mfma16(af, bq, aq[cf]);
      ak[cf] = mfma16(af, bk, ak[cf]);
      av[cf] = mfma16(af, bv, av[cf]);
    }
  }

#pragma unroll
  for (int cf = 0; cf < 4; cf++) {
#pragma unroll
    for (int r = 0; r < 4; r++) {
      const size_t row = (size_t)(rbase + g * 4 + r);
      const int col = cf * 16 + c;
      Q[row * AD + col] = f2bf(aq[cf][r] * 0.125f);  // fold 1/sqrt(64)
      K[row * AD + col] = f2bf(ak[cf][r]);
      V[row * AD + col] = f2bf(av[cf][r]);
    }
  }
}

// ---------------- Kernel 2: V transpose  [b][s][d] -> [b][d][s] -------------
__global__ __launch_bounds__(256) void transv_kernel(const u16* __restrict__ V,
                                                     u16* __restrict__ Vt) {
  const int b = blockIdx.y;
  const int sb = blockIdx.x * 64;
  __shared__ u16 t[64][65];
#pragma unroll
  for (int it = 0; it < 16; ++it) {
    int s = it * 4 + (threadIdx.x >> 6);
    int d = threadIdx.x & 63;
    t[s][d] = V[((size_t)b * SEQ + sb + s) * AD + d];
  }
  __syncthreads();
#pragma unroll
  for (int it = 0; it < 16; ++it) {
    int d = it * 4 + (threadIdx.x >> 6);
    int s = threadIdx.x & 63;
    Vt[(size_t)(b * AD + d) * SEQ + sb + s] = t[s][d];
  }
}

// ---------------- Kernel 3: flash attention partials (kv-split) --------------
// grid = 640: bx -> (batch b, unit u). u<96: full 16-tile off-diagonal chunks
// (heavy, dispatched first); u>=96: diagonal chunks (1..16 tiles, masked tail),
// ordered big-first. 4 waves/block, wave owns 16 q-rows.
__global__ __launch_bounds__(256) void flash_part(const u16* __restrict__ Q,
                                                  const u16* __restrict__ K,
                                                  const u16* __restrict__ Vt,
                                                  float* __restrict__ opart,
                                                  float* __restrict__ ml) {
  const int bx = blockIdx.x;
  const int b = bx & 3;
  const int u = bx >> 2;
  int q, c;
  if (u < 48)      { c = 0; q = 16 + u; }
  else if (u < 80) { c = 1; q = 32 + (u - 48); }
  else if (u < 96) { c = 2; q = 48 + (u - 80); }
  else { int d = u - 96; q = (d >> 4) * 16 + (15 - (d & 15)); c = q >> 4; }
  const bool diag = (c == (q >> 4));
  const int t0 = c * CHK;
  const int tc = diag ? (q - t0 + 1) : CHK;

  const int w = threadIdx.x >> 6;
  const int lane = threadIdx.x & 63;
  const int g = lane >> 4, cl = lane & 15;
  const int qw = q * 64 + w * 16;

  const u16* Qb = Q + (size_t)b * SEQ * AD;
  const u16* Kb = K + (size_t)b * SEQ * AD;
  const u16* Vb = Vt + (size_t)b * AD * SEQ;

  __shared__ __align__(16) u16 plds_all[4][16 * 64];
  u16* plds = plds_all[w];

  const short8 qf0 = *(const short8*)(Qb + (size_t)(qw + cl) * AD + g * 8);
  const short8 qf1 = *(const short8*)(Qb + (size_t)(qw + cl) * AD + 32 + g * 8);

  float mrow[4], lrow[4];
  f32x4 o[4];
#pragma unroll
  for (int r = 0; r < 4; r++) { mrow[r] = -INFINITY; lrow[r] = 0.f; }
#pragma unroll
  for (int cf = 0; cf < 4; cf++)
#pragma unroll
    for (int r = 0; r < 4; r++) o[cf][r] = 0.f;

  // preload K fragments for first tile
  short8 kf0[4], kf1[4];
#pragma unroll
  for (int cf = 0; cf < 4; cf++) {
    const u16* kp = Kb + (size_t)(t0 * 64 + cf * 16 + cl) * AD + g * 8;
    kf0[cf] = *(const short8*)(kp);
    kf1[cf] = *(const short8*)(kp + 32);
  }

  for (int kt = 0; kt < tc; ++kt) {
    const int kv0 = (t0 + kt) * 64;
    f32x4 s4[4];
#pragma unroll
    for (int cf = 0; cf < 4; cf++) {
      f32x4 z; z[0] = z[1] = z[2] = z[3] = 0.f;
      z = mfma16(qf0, kf0[cf], z);
      s4[cf] = mfma16(qf1, kf1[cf], z);
    }

    // prefetch next tile's K (overwrites dead kf regs; overlaps softmax+PV)
    if (kt + 1 < tc) {
#pragma unroll
      for (int cf = 0; cf < 4; cf++) {
        const u16* kp = Kb + (size_t)((t0 + kt + 1) * 64 + cf * 16 + cl) * AD + g * 8;
        kf0[cf] = *(const short8*)(kp);
        kf1[cf] = *(const short8*)(kp + 32);
      }
    }

    // ---- mask (diagonal tile only) + tile row-max ----
    float mt[4];
#pragma unroll
    for (int r = 0; r < 4; r++) mt[r] = -INFINITY;
    if (diag && kt == tc - 1) {
#pragma unroll
      for (int cf = 0; cf < 4; cf++) {
        const int kvg = kv0 + cf * 16 + cl;
#pragma unroll
        for (int r = 0; r < 4; r++) {
          float v = s4[cf][r];
          v = (kvg <= qw + g * 4 + r) ? v : -INFINITY;
          s4[cf][r] = v;
          mt[r] = fmaxf(mt[r], v);
        }
      }
    } else {
#pragma unroll
      for (int cf = 0; cf < 4; cf++)
#pragma unroll
        for (int r = 0; r < 4; r++) mt[r] = fmaxf(mt[r], s4[cf][r]);
    }
#pragma unroll
    for (int r = 0; r < 4; r++) {
      mt[r] = fmaxf(mt[r], __shfl_xor(mt[r], 1));
      mt[r] = fmaxf(mt[r], __shfl_xor(mt[r], 2));
      mt[r] = fmaxf(mt[r], __shfl_xor(mt[r], 4));
      mt[r] = fmaxf(mt[r], __shfl_xor(mt[r], 8));
    }

    float corr[4];
#pragma unroll
    for (int r = 0; r < 4; r++) {
      float mn = fmaxf(mrow[r], mt[r]);
      corr[r] = __expf(mrow[r] - mn);
      mrow[r] = mn;
    }

    float rs[4] = {0.f, 0.f, 0.f, 0.f};
#pragma unroll
    for (int cf = 0; cf < 4; cf++) {
#pragma unroll
      for (int r = 0; r < 4; r++) {
        float p = __expf(s4[cf][r] - mrow[r]);
        rs[r] += p;
        const int row = g * 4 + r;
        const int col = cf * 16 + cl;
        const int phys = (row << 6) | ((((col >> 3) ^ row) & 7) << 3) | (col & 7);
        plds[phys] = f2bf(p);
      }
    }
#pragma unroll
    for (int r = 0; r < 4; r++) {
      rs[r] += __shfl_xor(rs[r], 1);
      rs[r] += __shfl_xor(rs[r], 2);
      rs[r] += __shfl_xor(rs[r], 4);
      rs[r] += __shfl_xor(rs[r], 8);
      lrow[r] = lrow[r] * corr[r] + rs[r];
    }
#pragma unroll
    for (int cf = 0; cf < 4; cf++) {
      o[cf][0] *= corr[0]; o[cf][1] *= corr[1];
      o[cf][2] *= corr[2]; o[cf][3] *= corr[3];
    }

    asm volatile("s_waitcnt lgkmcnt(0)" ::: "memory");

#pragma unroll
    for (int ks = 0; ks < 2; ++ks) {
      const int oct = ks * 4 + g;
      const short8 pf = *(const short8*)(plds + (cl << 6) + (((oct ^ cl) & 7) << 3));
#pragma unroll
      for (int cf = 0; cf < 4; cf++) {
        const short8 vf = *(const short8*)(Vb + (size_t)(cf * 16 + cl) * SEQ + kv0 + ks * 32 + g * 8);
        o[cf] = mfma16(pf, vf, o[cf]);
      }
    }
  }

  // ---- write partials (unnormalized O, running m, l) ----
  const int qg = q * 4 + w;                 // 0..255 within batch
  const int k2 = qg >> 6;
  const int slot = b * 640 + 32 * k2 * (k2 + 1) + (qg & 63) * (k2 + 1) + c;

  if (cl == 0) {
#pragma unroll
    for (int r = 0; r < 4; r++) {
      ml[(size_t)slot * 32 + (g * 4 + r) * 2 + 0] = mrow[r];
      ml[(size_t)slot * 32 + (g * 4 + r) * 2 + 1] = lrow[r];
    }
  }
#pragma unroll
  for (int cf = 0; cf < 4; cf++)
#pragma unroll
    for (int r = 0; r < 4; r++)
      opart[(size_t)slot * 1024 + (g * 4 + r) * 64 + cf * 16 + cl] = o[cf][r];
}

// ---------------- Kernel 4: combine partials --------------------------------
__global__ __launch_bounds__(256) void combine_kernel(const float* __restrict__ opart,
                                                      const float* __restrict__ ml,
                                                      float* __restrict__ out) {
  const int tid = threadIdx.x;
  const int row = blockIdx.x * 16 + (tid >> 4);   // 0..16383
  const int d = (tid & 15) * 4;
  const int b = row >> 12;
  const int rowb = row & 4095;
  const int qg = rowb >> 4;
  const int r = rowb & 15;
  const int k2 = qg >> 6;
  const int nc = k2 + 1;
  const int sbase = b * 640 + 32 * k2 * (k2 + 1) + (qg & 63) * nc;

  float M = -INFINITY;
  float ms[4], ls[4];
  for (int cc = 0; cc < nc; cc++) {
    ms[cc] = ml[(size_t)(sbase + cc) * 32 + r * 2 + 0];
    ls[cc] = ml[(size_t)(sbase + cc) * 32 + r * 2 + 1];
    M = fmaxf(M, ms[cc]);
  }
  float L = 0.f;
  float4 acc = {0.f, 0.f, 0.f, 0.f};
  for (int cc = 0; cc < nc; cc++) {
    const float wgt = __expf(ms[cc] - M);
    L += ls[cc] * wgt;
    float4 ov = *(const float4*)(opart + (size_t)(sbase + cc) * 1024 + r * 64 + d);
    acc.x += ov.x * wgt; acc.y += ov.y * wgt;
    acc.z += ov.z * wgt; acc.w += ov.w * wgt;
  }
  const float inv = 1.0f / L;
  float4 res;
  res.x = rintf(acc.x * inv * 1.0e4f) * 1.0e-4f;
  res.y = rintf(acc.y * inv * 1.0e4f) * 1.0e-4f;
  res.z = rintf(acc.z * inv * 1.0e4f) * 1.0e-4f;
  res.w = rintf(acc.w * inv * 1.0e4f) * 1.0e-4f;
  *(float4*)(out + (size_t)row * AD + d) = res;
}

extern "C" void kernel_launch(void* const* d_in, const int* in_sizes, int n_in,
                              void* d_out, int out_size, void* d_ws, size_t ws_size,
                              hipStream_t stream) {
  const float* emb = (const float*)d_in[0];
  const float* Wq  = (const float*)d_in[1];
  const float* Wk  = (const float*)d_in[2];
  const float* Wv  = (const float*)d_in[3];
  float* out = (float*)d_out;

  char* ws = (char*)d_ws;
  u16* Wt = (u16*)ws;                               // 294912 B
  u16* Q  = (u16*)(ws + 294912);                    // 2 MiB each
  u16* K  = Q + (size_t)BS * AD;
  u16* V  = K + (size_t)BS * AD;
  u16* Vt = V + (size_t)BS * AD;
  float* opart = (float*)(ws + 294912 + 4 * (size_t)BS * AD * 2);  // 2560*4KB = 10.5 MB
  float* ml    = opart + (size_t)2560 * 1024;                      // 2560*128B

  wt_kernel<<<(3 * AD * EMB + 255) / 256, 256, 0, stream>>>(Wq, Wk, Wv, Wt);
  proj_kernel<<<BS / 64, 256, 0, stream>>>(emb, Wt, Q, K, V);
  transv_kernel<<<dim3(SEQ / 64, NB), 256, 0, stream>>>(V, Vt);
  flash_part<<<640, 256, 0, stream>>>(Q, K, Vt, opart, ml);
  combine_kernel<<<BS / 16, 256, 0, stream>>>(opart, ml, out);
}

// Round 3
// 148.315 us; speedup vs baseline: 1.5916x; 1.0091x over previous
//
#include <hip/hip_runtime.h>

#define NB 4
#define SEQ 4096
#define EMB 768
#define AD 64
#define BS (NB*SEQ)
#define CHK 16   // kv tiles (of 64) per chunk

typedef short short8 __attribute__((ext_vector_type(8)));
typedef float f32x4 __attribute__((ext_vector_type(4)));
typedef unsigned short u16;

__device__ __forceinline__ u16 f2bf(float f) {
  union { float f; unsigned u; } v; v.f = f;
  unsigned u = v.u;
  unsigned r = (u + 0x7FFFu + ((u >> 16) & 1u)) >> 16;  // RNE
  return (u16)r;
}

__device__ __forceinline__ unsigned cvt_pk_bf16(float lo, float hi) {
  unsigned r;
  asm("v_cvt_pk_bf16_f32 %0, %1, %2" : "=v"(r) : "v"(lo), "v"(hi));
  return r;
}

__device__ __forceinline__ f32x4 mfma16(short8 a, short8 b, f32x4 c) {
  return __builtin_amdgcn_mfma_f32_16x16x32_bf16(a, b, c, 0, 0, 0);
}

// ---------------- Kernel 0: weight transpose + bf16 cast --------------------
__global__ void wt_kernel(const float* __restrict__ Wq, const float* __restrict__ Wk,
                          const float* __restrict__ Wv, u16* __restrict__ Wt) {
  int idx = blockIdx.x * 256 + threadIdx.x;
  if (idx >= 3 * AD * EMB) return;
  int m   = idx / (AD * EMB);
  int rem = idx - m * (AD * EMB);
  int col = rem / EMB;
  int e   = rem - col * EMB;
  const float* W = (m == 0) ? Wq : (m == 1) ? Wk : Wv;
  Wt[idx] = f2bf(W[e * AD + col]);
}

// ---------------- Kernel 1: fused QKV projection (bf16 MFMA) ----------------
__global__ __launch_bounds__(256) void proj_kernel(const float* __restrict__ emb,
                                                   const u16* __restrict__ Wt,
                                                   u16* __restrict__ Q, u16* __restrict__ K,
                                                   u16* __restrict__ V) {
  const int w = threadIdx.x >> 6;
  const int lane = threadIdx.x & 63;
  const int g = lane >> 4, c = lane & 15;
  const int rbase = blockIdx.x * 64 + w * 16;

  f32x4 aq[4], ak[4], av[4];
#pragma unroll
  for (int cf = 0; cf < 4; cf++)
#pragma unroll
    for (int r = 0; r < 4; r++) { aq[cf][r] = 0.f; ak[cf][r] = 0.f; av[cf][r] = 0.f; }

  const float* arow = emb + (size_t)(rbase + c) * EMB;

  for (int e0 = 0; e0 < EMB; e0 += 32) {
    float4 x0 = *(const float4*)(arow + e0 + g * 8);
    float4 x1 = *(const float4*)(arow + e0 + g * 8 + 4);
    short8 af;
    af[0] = (short)f2bf(x0.x); af[1] = (short)f2bf(x0.y);
    af[2] = (short)f2bf(x0.z); af[3] = (short)f2bf(x0.w);
    af[4] = (short)f2bf(x1.x); af[5] = (short)f2bf(x1.y);
    af[6] = (short)f2bf(x1.z); af[7] = (short)f2bf(x1.w);
#pragma unroll
    for (int cf = 0; cf < 4; cf++) {
      const u16* wp = Wt + (size_t)(cf * 16 + c) * EMB + e0 + g * 8;
      short8 bq = *(const short8*)(wp);
      short8 bk = *(const short8*)(wp + AD * EMB);
      short8 bv = *(const short8*)(wp + 2 * AD * EMB);
      aq[cf] = mfma16(af, bq, aq[cf]);
      ak[cf] = mfma16(af, bk, ak[cf]);
      av[cf] = mfma16(af, bv, av[cf]);
    }
  }

#pragma unroll
  for (int cf = 0; cf < 4; cf++) {
#pragma unroll
    for (int r = 0; r < 4; r++) {
      const size_t row = (size_t)(rbase + g * 4 + r);
      const int col = cf * 16 + c;
      Q[row * AD + col] = f2bf(aq[cf][r] * 0.125f);  // fold 1/sqrt(64)
      K[row * AD + col] = f2bf(ak[cf][r]);
      V[row * AD + col] = f2bf(av[cf][r]);
    }
  }
}

// ---------------- Kernel 2: V transpose  [b][s][d] -> [b][d][s] -------------
__global__ __launch_bounds__(256) void transv_kernel(const u16* __restrict__ V,
                                                     u16* __restrict__ Vt) {
  const int b = blockIdx.y;
  const int sb = blockIdx.x * 64;
  __shared__ u16 t[64][65];
#pragma unroll
  for (int it = 0; it < 16; ++it) {
    int s = it * 4 + (threadIdx.x >> 6);
    int d = threadIdx.x & 63;
    t[s][d] = V[((size_t)b * SEQ + sb + s) * AD + d];
  }
  __syncthreads();
#pragma unroll
  for (int it = 0; it < 16; ++it) {
    int d = it * 4 + (threadIdx.x >> 6);
    int s = threadIdx.x & 63;
    Vt[(size_t)(b * AD + d) * SEQ + sb + s] = t[s][d];
  }
}

// ---------------- Kernel 3: flash attention partials (kv-split) --------------
// Swapped QK^T: S = mfma(K, Q) so each lane owns one q-column (q = lane&15).
// Softmax reduce = in-lane tree + 2 shuffles. P -> bf16 (cvt_pk) -> swizzled
// LDS (4x ds_write_b64) -> PV A-fragment (2x ds_read_b128). Defer-max THR=8.
__global__ __launch_bounds__(256) void flash_part(const u16* __restrict__ Q,
                                                  const u16* __restrict__ K,
                                                  const u16* __restrict__ Vt,
                                                  float* __restrict__ opart,
                                                  float* __restrict__ ml) {
  const int bx = blockIdx.x;
  const int b = bx & 3;
  const int u = bx >> 2;
  int q, c;
  if (u < 48)      { c = 0; q = 16 + u; }
  else if (u < 80) { c = 1; q = 32 + (u - 48); }
  else if (u < 96) { c = 2; q = 48 + (u - 80); }
  else { int d = u - 96; q = (d >> 4) * 16 + (15 - (d & 15)); c = q >> 4; }
  const bool diag = (c == (q >> 4));
  const int t0 = c * CHK;
  const int tc = diag ? (q - t0 + 1) : CHK;

  const int w = threadIdx.x >> 6;
  const int lane = threadIdx.x & 63;
  const int g = lane >> 4, cl = lane & 15;
  const int qw = q * 64 + w * 16;

  const u16* Qb = Q + (size_t)b * SEQ * AD;
  const u16* Kb = K + (size_t)b * SEQ * AD;
  const u16* Vb = Vt + (size_t)b * AD * SEQ;

  __shared__ __align__(16) u16 plds_all[4][16 * 64];
  char* plds = (char*)plds_all[w];
  const int swz = (cl & 7) << 4;
  const int prow = cl * 128;

  const short8 qf0 = *(const short8*)(Qb + (size_t)(qw + cl) * AD + g * 8);
  const short8 qf1 = *(const short8*)(Qb + (size_t)(qw + cl) * AD + 32 + g * 8);

  float mrow = -INFINITY, lrow = 0.f;
  f32x4 o[4];
#pragma unroll
  for (int cf = 0; cf < 4; cf++)
#pragma unroll
    for (int r = 0; r < 4; r++) o[cf][r] = 0.f;

  // preload K fragments for first tile
  short8 kf0[4], kf1[4];
#pragma unroll
  for (int cf = 0; cf < 4; cf++) {
    const u16* kp = Kb + (size_t)(t0 * 64 + cf * 16 + cl) * AD + g * 8;
    kf0[cf] = *(const short8*)(kp);
    kf1[cf] = *(const short8*)(kp + 32);
  }

  for (int kt = 0; kt < tc; ++kt) {
    const int kv0 = (t0 + kt) * 64;
    f32x4 s4[4];
    // ---- QK^T swapped: A = K rows (row = kv), B = Q rows (col = q) ----
#pragma unroll
    for (int cf = 0; cf < 4; cf++) {
      f32x4 z; z[0] = z[1] = z[2] = z[3] = 0.f;
      z = mfma16(kf0[cf], qf0, z);
      s4[cf] = mfma16(kf1[cf], qf1, z);
    }

    // prefetch next tile's K (overlaps softmax+PV)
    if (kt + 1 < tc) {
#pragma unroll
      for (int cf = 0; cf < 4; cf++) {
        const u16* kp = Kb + (size_t)((t0 + kt + 1) * 64 + cf * 16 + cl) * AD + g * 8;
        kf0[cf] = *(const short8*)(kp);
        kf1[cf] = *(const short8*)(kp + 32);
      }
    }

    // ---- causal mask (diagonal tile only); lane holds S[kv][q=qw+cl] ----
    if (diag && kt == tc - 1) {
#pragma unroll
      for (int cf = 0; cf < 4; cf++) {
        const int kvb = kv0 + cf * 16 + g * 4;
#pragma unroll
        for (int r = 0; r < 4; r++)
          s4[cf][r] = (kvb + r <= qw + cl) ? s4[cf][r] : -INFINITY;
      }
    }

    // ---- in-lane max tree + 2 cross-group shuffles ----
    float tm[4];
#pragma unroll
    for (int cf = 0; cf < 4; cf++)
      tm[cf] = fmaxf(fmaxf(s4[cf][0], s4[cf][1]), fmaxf(s4[cf][2], s4[cf][3]));
    float mt = fmaxf(fmaxf(tm[0], tm[1]), fmaxf(tm[2], tm[3]));
    mt = fmaxf(mt, __shfl_xor(mt, 16));
    mt = fmaxf(mt, __shfl_xor(mt, 32));

    // ---- defer-max: rescale only when max grew by > 8 ----
    if (!__all(mt <= mrow + 8.0f)) {
      const float mn = fmaxf(mrow, mt);
      const float corr = __expf(mrow - mn);
      mrow = mn;
      lrow *= corr;
      float cb[4];
#pragma unroll
      for (int r = 0; r < 4; r++) cb[r] = __shfl(corr, g * 20 + r);
#pragma unroll
      for (int cf = 0; cf < 4; cf++) {
        o[cf][0] *= cb[0]; o[cf][1] *= cb[1];
        o[cf][2] *= cb[2]; o[cf][3] *= cb[3];
      }
    }

    // ---- P = exp(S - m): in-lane; sum tree; pack to LDS ----
    float p[4][4];
    float ts[4];
#pragma unroll
    for (int cf = 0; cf < 4; cf++) {
      p[cf][0] = __expf(s4[cf][0] - mrow);
      p[cf][1] = __expf(s4[cf][1] - mrow);
      p[cf][2] = __expf(s4[cf][2] - mrow);
      p[cf][3] = __expf(s4[cf][3] - mrow);
      ts[cf] = (p[cf][0] + p[cf][1]) + (p[cf][2] + p[cf][3]);
    }
    float rs = (ts[0] + ts[1]) + (ts[2] + ts[3]);
    rs += __shfl_xor(rs, 16);
    rs += __shfl_xor(rs, 32);
    lrow += rs;

#pragma unroll
    for (int cf = 0; cf < 4; cf++) {
      uint2 val;
      val.x = cvt_pk_bf16(p[cf][0], p[cf][1]);
      val.y = cvt_pk_bf16(p[cf][2], p[cf][3]);
      *(uint2*)(plds + prow + (((cf * 32) + (g * 8)) ^ swz)) = val;
    }

    asm volatile("s_waitcnt lgkmcnt(0)" ::: "memory");

    // ---- PV: A = P rows (row = q = cl), B = Vt rows (col = d) ----
#pragma unroll
    for (int f = 0; f < 2; ++f) {
      const short8 pf = *(const short8*)(plds + prow + ((f * 64 + g * 16) ^ swz));
#pragma unroll
      for (int cf = 0; cf < 4; cf++) {
        const short8 vf = *(const short8*)(Vb + (size_t)(cf * 16 + cl) * SEQ + kv0 + f * 32 + g * 8);
        o[cf] = mfma16(pf, vf, o[cf]);
      }
    }
  }

  // ---- write partials (unnormalized O, running m, l) ----
  const int qg = q * 4 + w;                 // 0..255 within batch
  const int k2 = qg >> 6;
  const int slot = b * 640 + 32 * k2 * (k2 + 1) + (qg & 63) * (k2 + 1) + c;

  if (lane < 16) {  // g == 0: lane's q-column index cl = local q-row
    ml[(size_t)slot * 32 + cl * 2 + 0] = mrow;
    ml[(size_t)slot * 32 + cl * 2 + 1] = lrow;
  }
#pragma unroll
  for (int cf = 0; cf < 4; cf++)
#pragma unroll
    for (int r = 0; r < 4; r++)
      opart[(size_t)slot * 1024 + (g * 4 + r) * 64 + cf * 16 + cl] = o[cf][r];
}

// ---------------- Kernel 4: combine partials --------------------------------
__global__ __launch_bounds__(256) void combine_kernel(const float* __restrict__ opart,
                                                      const float* __restrict__ ml,
                                                      float* __restrict__ out) {
  const int tid = threadIdx.x;
  const int row = blockIdx.x * 16 + (tid >> 4);   // 0..16383
  const int d = (tid & 15) * 4;
  const int b = row >> 12;
  const int rowb = row & 4095;
  const int qg = rowb >> 4;
  const int r = rowb & 15;
  const int k2 = qg >> 6;
  const int nc = k2 + 1;
  const int sbase = b * 640 + 32 * k2 * (k2 + 1) + (qg & 63) * nc;

  float M = -INFINITY;
  float ms[4], ls[4];
  for (int cc = 0; cc < nc; cc++) {
    ms[cc] = ml[(size_t)(sbase + cc) * 32 + r * 2 + 0];
    ls[cc] = ml[(size_t)(sbase + cc) * 32 + r * 2 + 1];
    M = fmaxf(M, ms[cc]);
  }
  float L = 0.f;
  float4 acc = {0.f, 0.f, 0.f, 0.f};
  for (int cc = 0; cc < nc; cc++) {
    const float wgt = __expf(ms[cc] - M);
    L += ls[cc] * wgt;
    float4 ov = *(const float4*)(opart + (size_t)(sbase + cc) * 1024 + r * 64 + d);
    acc.x += ov.x * wgt; acc.y += ov.y * wgt;
    acc.z += ov.z * wgt; acc.w += ov.w * wgt;
  }
  const float inv = 1.0f / L;
  float4 res;
  res.x = rintf(acc.x * inv * 1.0e4f) * 1.0e-4f;
  res.y = rintf(acc.y * inv * 1.0e4f) * 1.0e-4f;
  res.z = rintf(acc.z * inv * 1.0e4f) * 1.0e-4f;
  res.w = rintf(acc.w * inv * 1.0e4f) * 1.0e-4f;
  *(float4*)(out + (size_t)row * AD + d) = res;
}

extern "C" void kernel_launch(void* const* d_in, const int* in_sizes, int n_in,
                              void* d_out, int out_size, void* d_ws, size_t ws_size,
                              hipStream_t stream) {
  const float* emb = (const float*)d_in[0];
  const float* Wq  = (const float*)d_in[1];
  const float* Wk  = (const float*)d_in[2];
  const float* Wv  = (const float*)d_in[3];
  float* out = (float*)d_out;

  char* ws = (char*)d_ws;
  u16* Wt = (u16*)ws;                               // 294912 B
  u16* Q  = (u16*)(ws + 294912);                    // 2 MiB each
  u16* K  = Q + (size_t)BS * AD;
  u16* V  = K + (size_t)BS * AD;
  u16* Vt = V + (size_t)BS * AD;
  float* opart = (float*)(ws + 294912 + 4 * (size_t)BS * AD * 2);  // 2560*4KB
  float* ml    = opart + (size_t)2560 * 1024;                      // 2560*128B

  wt_kernel<<<(3 * AD * EMB + 255) / 256, 256, 0, stream>>>(Wq, Wk, Wv, Wt);
  proj_kernel<<<BS / 64, 256, 0, stream>>>(emb, Wt, Q, K, V);
  transv_kernel<<<dim3(SEQ / 64, NB), 256, 0, stream>>>(V, Vt);
  flash_part<<<640, 256, 0, stream>>>(Q, K, Vt, opart, ml);
  combine_kernel<<<BS / 16, 256, 0, stream>>>(opart, ml, out);
}

// Round 4
// 145.011 us; speedup vs baseline: 1.6278x; 1.0228x over previous
//
#include <hip/hip_runtime.h>

#define NB 4
#define SEQ 4096
#define EMB 768
#define AD 64
#define BS (NB*SEQ)
#define CHK 16   // kv tiles (of 64) per chunk; waves of a block split these 4-way

typedef short short8 __attribute__((ext_vector_type(8)));
typedef float f32x4 __attribute__((ext_vector_type(4)));
typedef int   i32x2 __attribute__((ext_vector_type(2)));
typedef unsigned short u16;

__device__ __forceinline__ u16 f2bf(float f) {
  union { float f; unsigned u; } v; v.f = f;
  unsigned u = v.u;
  unsigned r = (u + 0x7FFFu + ((u >> 16) & 1u)) >> 16;  // RNE
  return (u16)r;
}

__device__ __forceinline__ unsigned cvt_pk_bf16(float lo, float hi) {
  unsigned r;
  asm("v_cvt_pk_bf16_f32 %0, %1, %2" : "=v"(r) : "v"(lo), "v"(hi));
  return r;
}

__device__ __forceinline__ f32x4 mfma16(short8 a, short8 b, f32x4 c) {
  return __builtin_amdgcn_mfma_f32_16x16x32_bf16(a, b, c, 0, 0, 0);
}

// pairwise combine across lanes (i, i^32): full-rate permlane when available
__device__ __forceinline__ float xor32_max(float x) {
#if __has_builtin(__builtin_amdgcn_permlane32_swap)
  i32x2 r = __builtin_amdgcn_permlane32_swap(__float_as_int(x), __float_as_int(x), false, false);
  return fmaxf(__int_as_float(r[0]), __int_as_float(r[1]));
#else
  return fmaxf(x, __shfl_xor(x, 32));
#endif
}
__device__ __forceinline__ float xor32_sum(float x) {
#if __has_builtin(__builtin_amdgcn_permlane32_swap)
  i32x2 r = __builtin_amdgcn_permlane32_swap(__float_as_int(x), __float_as_int(x), false, false);
  return __int_as_float(r[0]) + __int_as_float(r[1]);
#else
  return x + __shfl_xor(x, 32);
#endif
}

// ---------------- Kernel 0: weight transpose + bf16 cast --------------------
__global__ void wt_kernel(const float* __restrict__ Wq, const float* __restrict__ Wk,
                          const float* __restrict__ Wv, u16* __restrict__ Wt) {
  int idx = blockIdx.x * 256 + threadIdx.x;
  if (idx >= 3 * AD * EMB) return;
  int m   = idx / (AD * EMB);
  int rem = idx - m * (AD * EMB);
  int col = rem / EMB;
  int e   = rem - col * EMB;
  const float* W = (m == 0) ? Wq : (m == 1) ? Wk : Wv;
  Wt[idx] = f2bf(W[e * AD + col]);
}

// ---------------- Kernel 1: fused QKV projection + V transpose --------------
__global__ __launch_bounds__(256) void proj_kernel(const float* __restrict__ emb,
                                                   const u16* __restrict__ Wt,
                                                   u16* __restrict__ Q, u16* __restrict__ K,
                                                   u16* __restrict__ Vt) {
  const int w = threadIdx.x >> 6;
  const int lane = threadIdx.x & 63;
  const int g = lane >> 4, c = lane & 15;
  const int rbase = blockIdx.x * 64 + w * 16;

  __shared__ u16 t[64][65];

  f32x4 aq[4], ak[4], av[4];
#pragma unroll
  for (int cf = 0; cf < 4; cf++)
#pragma unroll
    for (int r = 0; r < 4; r++) { aq[cf][r] = 0.f; ak[cf][r] = 0.f; av[cf][r] = 0.f; }

  const float* arow = emb + (size_t)(rbase + c) * EMB;

  for (int e0 = 0; e0 < EMB; e0 += 32) {
    float4 x0 = *(const float4*)(arow + e0 + g * 8);
    float4 x1 = *(const float4*)(arow + e0 + g * 8 + 4);
    short8 af;
    af[0] = (short)f2bf(x0.x); af[1] = (short)f2bf(x0.y);
    af[2] = (short)f2bf(x0.z); af[3] = (short)f2bf(x0.w);
    af[4] = (short)f2bf(x1.x); af[5] = (short)f2bf(x1.y);
    af[6] = (short)f2bf(x1.z); af[7] = (short)f2bf(x1.w);
#pragma unroll
    for (int cf = 0; cf < 4; cf++) {
      const u16* wp = Wt + (size_t)(cf * 16 + c) * EMB + e0 + g * 8;
      short8 bq = *(const short8*)(wp);
      short8 bk = *(const short8*)(wp + AD * EMB);
      short8 bv = *(const short8*)(wp + 2 * AD * EMB);
      aq[cf] = mfma16(af, bq, aq[cf]);
      ak[cf] = mfma16(af, bk, ak[cf]);
      av[cf] = mfma16(af, bv, av[cf]);
    }
  }

#pragma unroll
  for (int cf = 0; cf < 4; cf++) {
#pragma unroll
    for (int r = 0; r < 4; r++) {
      const size_t row = (size_t)(rbase + g * 4 + r);
      const int col = cf * 16 + c;
      Q[row * AD + col] = f2bf(aq[cf][r] * 0.125f);  // fold 1/sqrt(64)
      K[row * AD + col] = f2bf(ak[cf][r]);
      t[w * 16 + g * 4 + r][col] = f2bf(av[cf][r]);  // stage V for transpose
    }
  }
  __syncthreads();
  const int bb = blockIdx.x >> 6;
  const int sb = (blockIdx.x & 63) * 64;
#pragma unroll
  for (int it = 0; it < 16; ++it) {
    const int d = it * 4 + w;
    Vt[(size_t)(bb * AD + d) * SEQ + sb + lane] = t[lane][d];
  }
}

// ---------------- Kernel 2: flash attention partials -------------------------
// Block = 16 q-rows (qg) x one 16-tile kv chunk (c). 4 waves round-robin the
// chunk's tiles (<=4 each), combine partials in LDS, emit ONE partial slot.
// Swapped QK^T (lane owns q-col), in-register softmax, defer-max THR=8,
// V cur-tile + K next-tile register prefetch, no explicit fences.
__global__ __launch_bounds__(256, 4) void flash_part(const u16* __restrict__ Q,
                                                     const u16* __restrict__ K,
                                                     const u16* __restrict__ Vt,
                                                     float* __restrict__ opart,
                                                     float* __restrict__ ml) {
  const int bx = blockIdx.x;
  const int b = bx & 3;
  const int u = bx >> 2;
  int qg, c;
  if (u < 192)      { c = 0; qg = 64 + u; }            // off-diagonal chunks first
  else if (u < 320) { c = 1; qg = 128 + (u - 192); }
  else if (u < 384) { c = 2; qg = 192 + (u - 320); }
  else { int d = u - 384; qg = (d >> 6) * 64 + (63 - (d & 63)); c = qg >> 6; }
  const int dtile = qg >> 2;                           // diagonal kv-tile
  const int t0 = c * CHK;
  const int tend = t0 + ((c == (qg >> 6)) ? (dtile - t0 + 1) : CHK);

  const int w = threadIdx.x >> 6;
  const int lane = threadIdx.x & 63;
  const int g = lane >> 4, cl = lane & 15;
  const int q0 = qg * 16;

  const u16* Qb = Q + (size_t)b * SEQ * AD;
  const u16* Kb = K + (size_t)b * SEQ * AD;
  const u16* Vb = Vt + (size_t)b * AD * SEQ;

  __shared__ __align__(16) u16 plds_all[4][16 * 64];
  __shared__ float mlp[4][16][2];
  __shared__ __align__(16) float ol[4][16 * 68];
  char* plds = (char*)plds_all[w];
  const int swz = (cl & 7) << 4;
  const int prow = cl * 128;

  const short8 qf0 = *(const short8*)(Qb + (size_t)(q0 + cl) * AD + g * 8);
  const short8 qf1 = *(const short8*)(Qb + (size_t)(q0 + cl) * AD + 32 + g * 8);

  float mrow = -INFINITY, lrow = 0.f;
  f32x4 o[4];
#pragma unroll
  for (int cf = 0; cf < 4; cf++)
#pragma unroll
    for (int r = 0; r < 4; r++) o[cf][r] = 0.f;

  // preload K fragments for this wave's first tile (t0+w <= 51, always in-bounds)
  short8 kf0[4], kf1[4];
#pragma unroll
  for (int cf = 0; cf < 4; cf++) {
    const u16* kp = Kb + (size_t)((t0 + w) * 64 + cf * 16 + cl) * AD + g * 8;
    kf0[cf] = *(const short8*)(kp);
    kf1[cf] = *(const short8*)(kp + 32);
  }

  for (int t = t0 + w; t < tend; t += 4) {
    const int kv0 = t * 64;
    // issue V loads for the CURRENT tile (consumed ~softmax-later in PV)
    short8 vf[8];
#pragma unroll
    for (int f = 0; f < 2; ++f)
#pragma unroll
      for (int cf = 0; cf < 4; cf++)
        vf[f * 4 + cf] = *(const short8*)(Vb + (size_t)(cf * 16 + cl) * SEQ + kv0 + f * 32 + g * 8);

    // QK^T swapped: A = K rows (row = kv), B = Q rows (col = q)
    f32x4 s4[4];
#pragma unroll
    for (int cf = 0; cf < 4; cf++) {
      f32x4 z; z[0] = z[1] = z[2] = z[3] = 0.f;
      z = mfma16(kf0[cf], qf0, z);
      s4[cf] = mfma16(kf1[cf], qf1, z);
    }

    // prefetch next tile's K (stride 4 tiles)
    if (t + 4 < tend) {
#pragma unroll
      for (int cf = 0; cf < 4; cf++) {
        const u16* kp = Kb + (size_t)((t + 4) * 64 + cf * 16 + cl) * AD + g * 8;
        kf0[cf] = *(const short8*)(kp);
        kf1[cf] = *(const short8*)(kp + 32);
      }
    }

    // causal mask (diagonal tile only); lane holds S[kv][q = q0+cl]
    if (t == dtile) {
#pragma unroll
      for (int cf = 0; cf < 4; cf++) {
        const int kvb = kv0 + cf * 16 + g * 4;
#pragma unroll
        for (int r = 0; r < 4; r++)
          s4[cf][r] = (kvb + r <= q0 + cl) ? s4[cf][r] : -INFINITY;
      }
    }

    // tile max: in-lane tree + xor16 (ds_swizzle) + xor32 (permlane)
    float tm[4];
#pragma unroll
    for (int cf = 0; cf < 4; cf++)
      tm[cf] = fmaxf(fmaxf(s4[cf][0], s4[cf][1]), fmaxf(s4[cf][2], s4[cf][3]));
    float mt = fmaxf(fmaxf(tm[0], tm[1]), fmaxf(tm[2], tm[3]));
    mt = fmaxf(mt, __shfl_xor(mt, 16));
    mt = xor32_max(mt);

    // defer-max: rescale only when max grew by > 8
    if (!__all(mt <= mrow + 8.0f)) {
      const float mn = fmaxf(mrow, mt);
      const float corr = __expf(mrow - mn);
      mrow = mn;
      lrow *= corr;
      float cb[4];
#pragma unroll
      for (int r = 0; r < 4; r++) cb[r] = __shfl(corr, g * 20 + r);
#pragma unroll
      for (int cf = 0; cf < 4; cf++) {
        o[cf][0] *= cb[0]; o[cf][1] *= cb[1];
        o[cf][2] *= cb[2]; o[cf][3] *= cb[3];
      }
    }

    // P = exp(S - m), in-lane sums, pack to LDS
    float p[4][4], ts[4];
#pragma unroll
    for (int cf = 0; cf < 4; cf++) {
      p[cf][0] = __expf(s4[cf][0] - mrow);
      p[cf][1] = __expf(s4[cf][1] - mrow);
      p[cf][2] = __expf(s4[cf][2] - mrow);
      p[cf][3] = __expf(s4[cf][3] - mrow);
      ts[cf] = (p[cf][0] + p[cf][1]) + (p[cf][2] + p[cf][3]);
    }
    float rs = (ts[0] + ts[1]) + (ts[2] + ts[3]);
    rs += __shfl_xor(rs, 16);
    rs = xor32_sum(rs);
    lrow += rs;

#pragma unroll
    for (int cf = 0; cf < 4; cf++) {
      uint2 val;
      val.x = cvt_pk_bf16(p[cf][0], p[cf][1]);
      val.y = cvt_pk_bf16(p[cf][2], p[cf][3]);
      *(uint2*)(plds + prow + (((cf * 32) + (g * 8)) ^ swz)) = val;
    }

    // PV: A = P rows (row = q = cl), B = Vt rows (col = d); compiler inserts
    // the minimal lgkm wait for the LDS RAW.
#pragma unroll
    for (int f = 0; f < 2; ++f) {
      const short8 pf = *(const short8*)(plds + prow + ((f * 64 + g * 16) ^ swz));
#pragma unroll
      for (int cf = 0; cf < 4; cf++)
        o[cf] = mfma16(pf, vf[f * 4 + cf], o[cf]);
    }
  }

  // ---- stage per-wave partials in LDS ----
  if (lane < 16) { mlp[w][cl][0] = mrow; mlp[w][cl][1] = lrow; }
#pragma unroll
  for (int cf = 0; cf < 4; cf++)
#pragma unroll
    for (int r = 0; r < 4; r++)
      ol[w][(g * 4 + r) * 68 + cf * 16 + cl] = o[cf][r];
  __syncthreads();

  // ---- intra-block combine (4 partials -> 1 slot) ----
  const int row16 = threadIdx.x >> 4;
  const int d4 = (threadIdx.x & 15) * 4;
  float ms[4], ls[4];
  float M = -INFINITY;
#pragma unroll
  for (int ww = 0; ww < 4; ww++) {
    ms[ww] = mlp[ww][row16][0];
    ls[ww] = mlp[ww][row16][1];
    M = fmaxf(M, ms[ww]);
  }
  float L = 0.f;
  float4 acc = {0.f, 0.f, 0.f, 0.f};
#pragma unroll
  for (int ww = 0; ww < 4; ww++) {
    const float wgt = __expf(ms[ww] - M);
    L += ls[ww] * wgt;
    float4 ov = *(const float4*)&ol[ww][row16 * 68 + d4];
    acc.x += ov.x * wgt; acc.y += ov.y * wgt;
    acc.z += ov.z * wgt; acc.w += ov.w * wgt;
  }

  const int k2 = qg >> 6;
  const int slot = b * 640 + 32 * k2 * (k2 + 1) + (qg & 63) * (k2 + 1) + c;
  *(float4*)(opart + (size_t)slot * 1024 + row16 * 64 + d4) = acc;
  if ((threadIdx.x & 15) == 0) {
    ml[(size_t)slot * 32 + row16 * 2 + 0] = M;
    ml[(size_t)slot * 32 + row16 * 2 + 1] = L;
  }
}

// ---------------- Kernel 3: combine partials --------------------------------
__global__ __launch_bounds__(256) void combine_kernel(const float* __restrict__ opart,
                                                      const float* __restrict__ ml,
                                                      float* __restrict__ out) {
  const int tid = threadIdx.x;
  const int row = blockIdx.x * 16 + (tid >> 4);   // 0..16383
  const int d = (tid & 15) * 4;
  const int b = row >> 12;
  const int rowb = row & 4095;
  const int qg = rowb >> 4;
  const int r = rowb & 15;
  const int k2 = qg >> 6;
  const int nc = k2 + 1;
  const int sbase = b * 640 + 32 * k2 * (k2 + 1) + (qg & 63) * nc;

  float M = -INFINITY;
  float ms[4], ls[4];
  for (int cc = 0; cc < nc; cc++) {
    ms[cc] = ml[(size_t)(sbase + cc) * 32 + r * 2 + 0];
    ls[cc] = ml[(size_t)(sbase + cc) * 32 + r * 2 + 1];
    M = fmaxf(M, ms[cc]);
  }
  float L = 0.f;
  float4 acc = {0.f, 0.f, 0.f, 0.f};
  for (int cc = 0; cc < nc; cc++) {
    const float wgt = __expf(ms[cc] - M);
    L += ls[cc] * wgt;
    float4 ov = *(const float4*)(opart + (size_t)(sbase + cc) * 1024 + r * 64 + d);
    acc.x += ov.x * wgt; acc.y += ov.y * wgt;
    acc.z += ov.z * wgt; acc.w += ov.w * wgt;
  }
  const float inv = 1.0f / L;
  float4 res;
  res.x = rintf(acc.x * inv * 1.0e4f) * 1.0e-4f;
  res.y = rintf(acc.y * inv * 1.0e4f) * 1.0e-4f;
  res.z = rintf(acc.z * inv * 1.0e4f) * 1.0e-4f;
  res.w = rintf(acc.w * inv * 1.0e4f) * 1.0e-4f;
  *(float4*)(out + (size_t)row * AD + d) = res;
}

extern "C" void kernel_launch(void* const* d_in, const int* in_sizes, int n_in,
                              void* d_out, int out_size, void* d_ws, size_t ws_size,
                              hipStream_t stream) {
  const float* emb = (const float*)d_in[0];
  const float* Wq  = (const float*)d_in[1];
  const float* Wk  = (const float*)d_in[2];
  const float* Wv  = (const float*)d_in[3];
  float* out = (float*)d_out;

  char* ws = (char*)d_ws;
  u16* Wt = (u16*)ws;                               // 294912 B
  u16* Q  = (u16*)(ws + 294912);                    // 2 MiB each
  u16* K  = Q + (size_t)BS * AD;
  u16* Vt = K + (size_t)BS * AD;
  float* opart = (float*)(ws + 294912 + 3 * (size_t)BS * AD * 2);  // 2560*4KB
  float* ml    = opart + (size_t)2560 * 1024;                      // 2560*128B

  wt_kernel<<<(3 * AD * EMB + 255) / 256, 256, 0, stream>>>(Wq, Wk, Wv, Wt);
  proj_kernel<<<BS / 64, 256, 0, stream>>>(emb, Wt, Q, K, Vt);
  flash_part<<<2560, 256, 0, stream>>>(Q, K, Vt, opart, ml);
  combine_kernel<<<BS / 16, 256, 0, stream>>>(opart, ml, out);
}

// Round 5
// 127.395 us; speedup vs baseline: 1.8529x; 1.1383x over previous
//
#include <hip/hip_runtime.h>

#define NB 4
#define SEQ 4096
#define EMB 768
#define AD 64
#define BS (NB*SEQ)
#define CHK 16   // kv tiles (of 64) per chunk; waves of a block split these 4-way

typedef short short8 __attribute__((ext_vector_type(8)));
typedef float f32x4 __attribute__((ext_vector_type(4)));
typedef int   i32x2 __attribute__((ext_vector_type(2)));
typedef unsigned short u16;

__device__ __forceinline__ u16 f2bf(float f) {
  union { float f; unsigned u; } v; v.f = f;
  unsigned u = v.u;
  unsigned r = (u + 0x7FFFu + ((u >> 16) & 1u)) >> 16;  // RNE
  return (u16)r;
}

__device__ __forceinline__ unsigned cvt_pk_bf16(float lo, float hi) {
  unsigned r;
  asm("v_cvt_pk_bf16_f32 %0, %1, %2" : "=v"(r) : "v"(lo), "v"(hi));
  return r;
}

__device__ __forceinline__ f32x4 mfma16(short8 a, short8 b, f32x4 c) {
  return __builtin_amdgcn_mfma_f32_16x16x32_bf16(a, b, c, 0, 0, 0);
}

// pairwise combine across lanes (i, i^16) and (i, i^32): VALU-rate permlane
__device__ __forceinline__ float xor16_max(float x) {
#if __has_builtin(__builtin_amdgcn_permlane16_swap)
  i32x2 r = __builtin_amdgcn_permlane16_swap(__float_as_int(x), __float_as_int(x), false, false);
  return fmaxf(__int_as_float(r[0]), __int_as_float(r[1]));
#else
  return fmaxf(x, __shfl_xor(x, 16));
#endif
}
__device__ __forceinline__ float xor16_sum(float x) {
#if __has_builtin(__builtin_amdgcn_permlane16_swap)
  i32x2 r = __builtin_amdgcn_permlane16_swap(__float_as_int(x), __float_as_int(x), false, false);
  return __int_as_float(r[0]) + __int_as_float(r[1]);
#else
  return x + __shfl_xor(x, 16);
#endif
}
__device__ __forceinline__ float xor32_max(float x) {
#if __has_builtin(__builtin_amdgcn_permlane32_swap)
  i32x2 r = __builtin_amdgcn_permlane32_swap(__float_as_int(x), __float_as_int(x), false, false);
  return fmaxf(__int_as_float(r[0]), __int_as_float(r[1]));
#else
  return fmaxf(x, __shfl_xor(x, 32));
#endif
}
__device__ __forceinline__ float xor32_sum(float x) {
#if __has_builtin(__builtin_amdgcn_permlane32_swap)
  i32x2 r = __builtin_amdgcn_permlane32_swap(__float_as_int(x), __float_as_int(x), false, false);
  return __int_as_float(r[0]) + __int_as_float(r[1]);
#else
  return x + __shfl_xor(x, 32);
#endif
}

// ---------------- Kernel 0: weight transpose + bf16 cast --------------------
__global__ void wt_kernel(const float* __restrict__ Wq, const float* __restrict__ Wk,
                          const float* __restrict__ Wv, u16* __restrict__ Wt) {
  int idx = blockIdx.x * 256 + threadIdx.x;
  if (idx >= 3 * AD * EMB) return;
  int m   = idx / (AD * EMB);
  int rem = idx - m * (AD * EMB);
  int col = rem / EMB;
  int e   = rem - col * EMB;
  const float* W = (m == 0) ? Wq : (m == 1) ? Wk : Wv;
  Wt[idx] = f2bf(W[e * AD + col]);
}

// ---------------- Kernel 1: fused QKV projection + V transpose --------------
// Block = 64 rows x 8 waves: 4 row-groups (w&3) x 2 EMB halves (w>>2).
// eh=1 waves stage f32 partials in LDS; eh=0 waves combine + emit Q/K/Vt.
__global__ __launch_bounds__(512) void proj_kernel(const float* __restrict__ emb,
                                                   const u16* __restrict__ Wt,
                                                   u16* __restrict__ Q, u16* __restrict__ K,
                                                   u16* __restrict__ Vt) {
  const int w = threadIdx.x >> 6;
  const int lane = threadIdx.x & 63;
  const int g = lane >> 4, c = lane & 15;
  const int wr = w & 3;                 // row group (16 rows)
  const int eh = w >> 2;                // EMB half
  const int rbase = blockIdx.x * 64 + wr * 16;

  __shared__ float part[4][3 * 16 * 66];   // [wr][m*1056 + row*66 + col]
  __shared__ u16 t[64][65];                // V transpose staging

  f32x4 aq[4], ak[4], av[4];
#pragma unroll
  for (int cf = 0; cf < 4; cf++)
#pragma unroll
    for (int r = 0; r < 4; r++) { aq[cf][r] = 0.f; ak[cf][r] = 0.f; av[cf][r] = 0.f; }

  const float* arow = emb + (size_t)(rbase + c) * EMB + eh * 384;

  for (int e0 = 0; e0 < 384; e0 += 32) {
    float4 x0 = *(const float4*)(arow + e0 + g * 8);
    float4 x1 = *(const float4*)(arow + e0 + g * 8 + 4);
    short8 af;
    af[0] = (short)f2bf(x0.x); af[1] = (short)f2bf(x0.y);
    af[2] = (short)f2bf(x0.z); af[3] = (short)f2bf(x0.w);
    af[4] = (short)f2bf(x1.x); af[5] = (short)f2bf(x1.y);
    af[6] = (short)f2bf(x1.z); af[7] = (short)f2bf(x1.w);
#pragma unroll
    for (int cf = 0; cf < 4; cf++) {
      const u16* wp = Wt + (size_t)(cf * 16 + c) * EMB + eh * 384 + e0 + g * 8;
      short8 bq = *(const short8*)(wp);
      short8 bk = *(const short8*)(wp + AD * EMB);
      short8 bv = *(const short8*)(wp + 2 * AD * EMB);
      aq[cf] = mfma16(af, bq, aq[cf]);
      ak[cf] = mfma16(af, bk, ak[cf]);
      av[cf] = mfma16(af, bv, av[cf]);
    }
  }

  if (eh == 1) {
#pragma unroll
    for (int cf = 0; cf < 4; cf++)
#pragma unroll
      for (int r = 0; r < 4; r++) {
        const int row = g * 4 + r, col = cf * 16 + c;
        part[wr][0 * 1056 + row * 66 + col] = aq[cf][r];
        part[wr][1 * 1056 + row * 66 + col] = ak[cf][r];
        part[wr][2 * 1056 + row * 66 + col] = av[cf][r];
      }
  }
  __syncthreads();
  if (eh == 0) {
#pragma unroll
    for (int cf = 0; cf < 4; cf++) {
#pragma unroll
      for (int r = 0; r < 4; r++) {
        const int row = g * 4 + r, col = cf * 16 + c;
        const float sq = aq[cf][r] + part[wr][0 * 1056 + row * 66 + col];
        const float sk = ak[cf][r] + part[wr][1 * 1056 + row * 66 + col];
        const float sv = av[cf][r] + part[wr][2 * 1056 + row * 66 + col];
        const size_t grow = (size_t)(rbase + row);
        Q[grow * AD + col] = f2bf(sq * 0.125f);  // fold 1/sqrt(64)
        K[grow * AD + col] = f2bf(sk);
        t[wr * 16 + row][col] = f2bf(sv);        // stage V for transpose
      }
    }
  }
  __syncthreads();
  const int bb = blockIdx.x >> 6;
  const int sb = (blockIdx.x & 63) * 64;
#pragma unroll
  for (int it = 0; it < 8; ++it) {
    const int d = it * 8 + w;
    Vt[(size_t)(bb * AD + d) * SEQ + sb + lane] = t[lane][d];
  }
}

// ---------------- Kernel 2: flash attention partials -------------------------
// Block = 16 q-rows (qg) x one 16-tile kv chunk (c). 4 waves round-robin the
// chunk's tiles (<=4 each), combine partials in LDS, emit ONE partial slot.
// Swapped QK^T (lane owns q-col), in-register softmax fused into immediate
// LDS writes (no p[][] array), V loaded per-f-slice at PV (no long-lived
// prefetch) -- both to avoid the R4 scratch spills. Defer-max THR=8.
__global__ __launch_bounds__(256, 4) void flash_part(const u16* __restrict__ Q,
                                                     const u16* __restrict__ K,
                                                     const u16* __restrict__ Vt,
                                                     float* __restrict__ opart,
                                                     float* __restrict__ ml) {
  const int bx = blockIdx.x;
  const int b = bx & 3;
  const int u = bx >> 2;
  int qg, c;
  if (u < 192)      { c = 0; qg = 64 + u; }            // off-diagonal chunks first
  else if (u < 320) { c = 1; qg = 128 + (u - 192); }
  else if (u < 384) { c = 2; qg = 192 + (u - 320); }
  else { int d = u - 384; qg = (d >> 6) * 64 + (63 - (d & 63)); c = qg >> 6; }
  const int dtile = qg >> 2;                           // diagonal kv-tile
  const int t0 = c * CHK;
  const int tend = t0 + ((c == (qg >> 6)) ? (dtile - t0 + 1) : CHK);

  const int w = threadIdx.x >> 6;
  const int lane = threadIdx.x & 63;
  const int g = lane >> 4, cl = lane & 15;
  const int q0 = qg * 16;

  const u16* Qb = Q + (size_t)b * SEQ * AD;
  const u16* Kb = K + (size_t)b * SEQ * AD;
  const u16* Vb = Vt + (size_t)b * AD * SEQ;

  __shared__ __align__(16) u16 plds_all[4][16 * 64];
  __shared__ float mlp[4][16][2];
  __shared__ __align__(16) float ol[4][16 * 68];
  char* plds = (char*)plds_all[w];
  const int swz = (cl & 7) << 4;
  const int prow = cl * 128;

  const short8 qf0 = *(const short8*)(Qb + (size_t)(q0 + cl) * AD + g * 8);
  const short8 qf1 = *(const short8*)(Qb + (size_t)(q0 + cl) * AD + 32 + g * 8);

  float mrow = -INFINITY, lrow = 0.f;
  f32x4 o[4];
#pragma unroll
  for (int cf = 0; cf < 4; cf++)
#pragma unroll
    for (int r = 0; r < 4; r++) o[cf][r] = 0.f;

  // preload K fragments for this wave's first tile
  short8 kf0[4], kf1[4];
#pragma unroll
  for (int cf = 0; cf < 4; cf++) {
    const u16* kp = Kb + (size_t)((t0 + w) * 64 + cf * 16 + cl) * AD + g * 8;
    kf0[cf] = *(const short8*)(kp);
    kf1[cf] = *(const short8*)(kp + 32);
  }

  for (int t = t0 + w; t < tend; t += 4) {
    const int kv0 = t * 64;

    // QK^T swapped: A = K rows (row = kv), B = Q rows (col = q)
    f32x4 s4[4];
#pragma unroll
    for (int cf = 0; cf < 4; cf++) {
      f32x4 z; z[0] = z[1] = z[2] = z[3] = 0.f;
      z = mfma16(kf0[cf], qf0, z);
      s4[cf] = mfma16(kf1[cf], qf1, z);
    }

    // prefetch next tile's K (stride 4 tiles), reusing kf registers
    if (t + 4 < tend) {
#pragma unroll
      for (int cf = 0; cf < 4; cf++) {
        const u16* kp = Kb + (size_t)((t + 4) * 64 + cf * 16 + cl) * AD + g * 8;
        kf0[cf] = *(const short8*)(kp);
        kf1[cf] = *(const short8*)(kp + 32);
      }
    }

    // causal mask (diagonal tile only); lane holds S[kv][q = q0+cl]
    if (t == dtile) {
#pragma unroll
      for (int cf = 0; cf < 4; cf++) {
        const int kvb = kv0 + cf * 16 + g * 4;
#pragma unroll
        for (int r = 0; r < 4; r++)
          s4[cf][r] = (kvb + r <= q0 + cl) ? s4[cf][r] : -INFINITY;
      }
    }

    // tile max: in-lane tree + permlane xor16/xor32 (all VALU)
    float tm[4];
#pragma unroll
    for (int cf = 0; cf < 4; cf++)
      tm[cf] = fmaxf(fmaxf(s4[cf][0], s4[cf][1]), fmaxf(s4[cf][2], s4[cf][3]));
    float mt = fmaxf(fmaxf(tm[0], tm[1]), fmaxf(tm[2], tm[3]));
    mt = xor16_max(mt);
    mt = xor32_max(mt);

    // defer-max: rescale only when max grew by > 8
    if (!__all(mt <= mrow + 8.0f)) {
      const float mn = fmaxf(mrow, mt);
      const float corr = __expf(mrow - mn);
      mrow = mn;
      lrow *= corr;
      float cb[4];
#pragma unroll
      for (int r = 0; r < 4; r++) cb[r] = __shfl(corr, g * 20 + r);
#pragma unroll
      for (int cf = 0; cf < 4; cf++) {
        o[cf][0] *= cb[0]; o[cf][1] *= cb[1];
        o[cf][2] *= cb[2]; o[cf][3] *= cb[3];
      }
    }

    // P = exp(S - m): fused exp -> sum -> pack -> LDS per cf (no p[][] array)
    float rs = 0.f;
#pragma unroll
    for (int cf = 0; cf < 4; cf++) {
      const float p0 = __expf(s4[cf][0] - mrow);
      const float p1 = __expf(s4[cf][1] - mrow);
      const float p2 = __expf(s4[cf][2] - mrow);
      const float p3 = __expf(s4[cf][3] - mrow);
      rs += (p0 + p1) + (p2 + p3);
      uint2 val;
      val.x = cvt_pk_bf16(p0, p1);
      val.y = cvt_pk_bf16(p2, p3);
      *(uint2*)(plds + prow + (((cf * 32) + (g * 8)) ^ swz)) = val;
    }
    rs = xor16_sum(rs);
    rs = xor32_sum(rs);
    lrow += rs;

    // PV: A = P rows (row = q = cl), B = Vt rows (col = d); V loaded per
    // f-slice right before use (short live range, no spill)
#pragma unroll
    for (int f = 0; f < 2; ++f) {
      short8 vfa[4];
#pragma unroll
      for (int cf = 0; cf < 4; cf++)
        vfa[cf] = *(const short8*)(Vb + (size_t)(cf * 16 + cl) * SEQ + kv0 + f * 32 + g * 8);
      const short8 pf = *(const short8*)(plds + prow + ((f * 64 + g * 16) ^ swz));
#pragma unroll
      for (int cf = 0; cf < 4; cf++)
        o[cf] = mfma16(pf, vfa[cf], o[cf]);
    }
  }

  // ---- stage per-wave partials in LDS ----
  if (lane < 16) { mlp[w][cl][0] = mrow; mlp[w][cl][1] = lrow; }
#pragma unroll
  for (int cf = 0; cf < 4; cf++)
#pragma unroll
    for (int r = 0; r < 4; r++)
      ol[w][(g * 4 + r) * 68 + cf * 16 + cl] = o[cf][r];
  __syncthreads();

  // ---- intra-block combine (4 partials -> 1 slot) ----
  const int row16 = threadIdx.x >> 4;
  const int d4 = (threadIdx.x & 15) * 4;
  float ms[4], ls[4];
  float M = -INFINITY;
#pragma unroll
  for (int ww = 0; ww < 4; ww++) {
    ms[ww] = mlp[ww][row16][0];
    ls[ww] = mlp[ww][row16][1];
    M = fmaxf(M, ms[ww]);
  }
  float L = 0.f;
  float4 acc = {0.f, 0.f, 0.f, 0.f};
#pragma unroll
  for (int ww = 0; ww < 4; ww++) {
    const float wgt = __expf(ms[ww] - M);
    L += ls[ww] * wgt;
    float4 ov = *(const float4*)&ol[ww][row16 * 68 + d4];
    acc.x += ov.x * wgt; acc.y += ov.y * wgt;
    acc.z += ov.z * wgt; acc.w += ov.w * wgt;
  }

  const int k2 = qg >> 6;
  const int slot = b * 640 + 32 * k2 * (k2 + 1) + (qg & 63) * (k2 + 1) + c;
  *(float4*)(opart + (size_t)slot * 1024 + row16 * 64 + d4) = acc;
  if ((threadIdx.x & 15) == 0) {
    ml[(size_t)slot * 32 + row16 * 2 + 0] = M;
    ml[(size_t)slot * 32 + row16 * 2 + 1] = L;
  }
}

// ---------------- Kernel 3: combine partials --------------------------------
__global__ __launch_bounds__(256) void combine_kernel(const float* __restrict__ opart,
                                                      const float* __restrict__ ml,
                                                      float* __restrict__ out) {
  const int tid = threadIdx.x;
  const int row = blockIdx.x * 16 + (tid >> 4);   // 0..16383
  const int d = (tid & 15) * 4;
  const int b = row >> 12;
  const int rowb = row & 4095;
  const int qg = rowb >> 4;
  const int r = rowb & 15;
  const int k2 = qg >> 6;
  const int nc = k2 + 1;
  const int sbase = b * 640 + 32 * k2 * (k2 + 1) + (qg & 63) * nc;

  float M = -INFINITY;
  float ms[4], ls[4];
  for (int cc = 0; cc < nc; cc++) {
    ms[cc] = ml[(size_t)(sbase + cc) * 32 + r * 2 + 0];
    ls[cc] = ml[(size_t)(sbase + cc) * 32 + r * 2 + 1];
    M = fmaxf(M, ms[cc]);
  }
  float L = 0.f;
  float4 acc = {0.f, 0.f, 0.f, 0.f};
  for (int cc = 0; cc < nc; cc++) {
    const float wgt = __expf(ms[cc] - M);
    L += ls[cc] * wgt;
    float4 ov = *(const float4*)(opart + (size_t)(sbase + cc) * 1024 + r * 64 + d);
    acc.x += ov.x * wgt; acc.y += ov.y * wgt;
    acc.z += ov.z * wgt; acc.w += ov.w * wgt;
  }
  const float inv = 1.0f / L;
  float4 res;
  res.x = rintf(acc.x * inv * 1.0e4f) * 1.0e-4f;
  res.y = rintf(acc.y * inv * 1.0e4f) * 1.0e-4f;
  res.z = rintf(acc.z * inv * 1.0e4f) * 1.0e-4f;
  res.w = rintf(acc.w * inv * 1.0e4f) * 1.0e-4f;
  *(float4*)(out + (size_t)row * AD + d) = res;
}

extern "C" void kernel_launch(void* const* d_in, const int* in_sizes, int n_in,
                              void* d_out, int out_size, void* d_ws, size_t ws_size,
                              hipStream_t stream) {
  const float* emb = (const float*)d_in[0];
  const float* Wq  = (const float*)d_in[1];
  const float* Wk  = (const float*)d_in[2];
  const float* Wv  = (const float*)d_in[3];
  float* out = (float*)d_out;

  char* ws = (char*)d_ws;
  u16* Wt = (u16*)ws;                               // 294912 B
  u16* Q  = (u16*)(ws + 294912);                    // 2 MiB each
  u16* K  = Q + (size_t)BS * AD;
  u16* Vt = K + (size_t)BS * AD;
  float* opart = (float*)(ws + 294912 + 3 * (size_t)BS * AD * 2);  // 2560*4KB
  float* ml    = opart + (size_t)2560 * 1024;                      // 2560*128B

  wt_kernel<<<(3 * AD * EMB + 255) / 256, 256, 0, stream>>>(Wq, Wk, Wv, Wt);
  proj_kernel<<<BS / 64, 512, 0, stream>>>(emb, Wt, Q, K, Vt);
  flash_part<<<2560, 256, 0, stream>>>(Q, K, Vt, opart, ml);
  combine_kernel<<<BS / 16, 256, 0, stream>>>(opart, ml, out);
}

// Round 6
// 83.420 us; speedup vs baseline: 2.8297x; 1.5271x over previous
//
#include <hip/hip_runtime.h>

#define NB 4
#define SEQ 4096
#define EMB 768
#define AD 64
#define BS (NB*SEQ)
#define CHK 16   // kv tiles (of 64) per chunk

typedef short short8 __attribute__((ext_vector_type(8)));
typedef float f32x4 __attribute__((ext_vector_type(4)));
typedef int   i32x2 __attribute__((ext_vector_type(2)));
typedef unsigned short u16;

__device__ __forceinline__ u16 f2bf(float f) {
  union { float f; unsigned u; } v; v.f = f;
  unsigned u = v.u;
  unsigned r = (u + 0x7FFFu + ((u >> 16) & 1u)) >> 16;  // RNE
  return (u16)r;
}

__device__ __forceinline__ unsigned cvt_pk_bf16(float lo, float hi) {
  unsigned r;
  asm("v_cvt_pk_bf16_f32 %0, %1, %2" : "=v"(r) : "v"(lo), "v"(hi));
  return r;
}

__device__ __forceinline__ f32x4 mfma16(short8 a, short8 b, f32x4 c) {
  return __builtin_amdgcn_mfma_f32_16x16x32_bf16(a, b, c, 0, 0, 0);
}

// async global->LDS, 16B per lane; LDS dest = uniform base + lane*16
__device__ __forceinline__ void gload16(const u16* g, u16* l) {
  __builtin_amdgcn_global_load_lds(
      (const __attribute__((address_space(1))) unsigned*)g,
      (__attribute__((address_space(3))) unsigned*)l, 16, 0, 0);
}

__device__ __forceinline__ float xor16_max(float x) {
#if __has_builtin(__builtin_amdgcn_permlane16_swap)
  i32x2 r = __builtin_amdgcn_permlane16_swap(__float_as_int(x), __float_as_int(x), false, false);
  return fmaxf(__int_as_float(r[0]), __int_as_float(r[1]));
#else
  return fmaxf(x, __shfl_xor(x, 16));
#endif
}
__device__ __forceinline__ float xor16_sum(float x) {
#if __has_builtin(__builtin_amdgcn_permlane16_swap)
  i32x2 r = __builtin_amdgcn_permlane16_swap(__float_as_int(x), __float_as_int(x), false, false);
  return __int_as_float(r[0]) + __int_as_float(r[1]);
#else
  return x + __shfl_xor(x, 16);
#endif
}
__device__ __forceinline__ float xor32_max(float x) {
#if __has_builtin(__builtin_amdgcn_permlane32_swap)
  i32x2 r = __builtin_amdgcn_permlane32_swap(__float_as_int(x), __float_as_int(x), false, false);
  return fmaxf(__int_as_float(r[0]), __int_as_float(r[1]));
#else
  return fmaxf(x, __shfl_xor(x, 32));
#endif
}
__device__ __forceinline__ float xor32_sum(float x) {
#if __has_builtin(__builtin_amdgcn_permlane32_swap)
  i32x2 r = __builtin_amdgcn_permlane32_swap(__float_as_int(x), __float_as_int(x), false, false);
  return __int_as_float(r[0]) + __int_as_float(r[1]);
#else
  return x + __shfl_xor(x, 32);
#endif
}

// ---------------- Kernel 0: weight transpose + bf16 cast --------------------
__global__ void wt_kernel(const float* __restrict__ Wq, const float* __restrict__ Wk,
                          const float* __restrict__ Wv, u16* __restrict__ Wt) {
  int idx = blockIdx.x * 256 + threadIdx.x;
  if (idx >= 3 * AD * EMB) return;
  int m   = idx / (AD * EMB);
  int rem = idx - m * (AD * EMB);
  int col = rem / EMB;
  int e   = rem - col * EMB;
  const float* W = (m == 0) ? Wq : (m == 1) ? Wk : Wv;
  Wt[idx] = f2bf(W[e * AD + col]);
}

// ---------------- Kernel 1: fused QKV projection + V transpose --------------
__global__ __launch_bounds__(512) void proj_kernel(const float* __restrict__ emb,
                                                   const u16* __restrict__ Wt,
                                                   u16* __restrict__ Q, u16* __restrict__ K,
                                                   u16* __restrict__ Vt) {
  const int w = threadIdx.x >> 6;
  const int lane = threadIdx.x & 63;
  const int g = lane >> 4, c = lane & 15;
  const int wr = w & 3;                 // row group (16 rows)
  const int eh = w >> 2;                // EMB half
  const int rbase = blockIdx.x * 64 + wr * 16;

  __shared__ float part[4][3 * 16 * 66];   // [wr][m*1056 + row*66 + col]
  __shared__ u16 t[64][65];                // V transpose staging

  f32x4 aq[4], ak[4], av[4];
#pragma unroll
  for (int cf = 0; cf < 4; cf++)
#pragma unroll
    for (int r = 0; r < 4; r++) { aq[cf][r] = 0.f; ak[cf][r] = 0.f; av[cf][r] = 0.f; }

  const float* arow = emb + (size_t)(rbase + c) * EMB + eh * 384;

  for (int e0 = 0; e0 < 384; e0 += 32) {
    float4 x0 = *(const float4*)(arow + e0 + g * 8);
    float4 x1 = *(const float4*)(arow + e0 + g * 8 + 4);
    short8 af;
    af[0] = (short)f2bf(x0.x); af[1] = (short)f2bf(x0.y);
    af[2] = (short)f2bf(x0.z); af[3] = (short)f2bf(x0.w);
    af[4] = (short)f2bf(x1.x); af[5] = (short)f2bf(x1.y);
    af[6] = (short)f2bf(x1.z); af[7] = (short)f2bf(x1.w);
#pragma unroll
    for (int cf = 0; cf < 4; cf++) {
      const u16* wp = Wt + (size_t)(cf * 16 + c) * EMB + eh * 384 + e0 + g * 8;
      short8 bq = *(const short8*)(wp);
      short8 bk = *(const short8*)(wp + AD * EMB);
      short8 bv = *(const short8*)(wp + 2 * AD * EMB);
      aq[cf] = mfma16(af, bq, aq[cf]);
      ak[cf] = mfma16(af, bk, ak[cf]);
      av[cf] = mfma16(af, bv, av[cf]);
    }
  }

  if (eh == 1) {
#pragma unroll
    for (int cf = 0; cf < 4; cf++)
#pragma unroll
      for (int r = 0; r < 4; r++) {
        const int row = g * 4 + r, col = cf * 16 + c;
        part[wr][0 * 1056 + row * 66 + col] = aq[cf][r];
        part[wr][1 * 1056 + row * 66 + col] = ak[cf][r];
        part[wr][2 * 1056 + row * 66 + col] = av[cf][r];
      }
  }
  __syncthreads();
  if (eh == 0) {
#pragma unroll
    for (int cf = 0; cf < 4; cf++) {
#pragma unroll
      for (int r = 0; r < 4; r++) {
        const int row = g * 4 + r, col = cf * 16 + c;
        const float sq = aq[cf][r] + part[wr][0 * 1056 + row * 66 + col];
        const float sk = ak[cf][r] + part[wr][1 * 1056 + row * 66 + col];
        const float sv = av[cf][r] + part[wr][2 * 1056 + row * 66 + col];
        const size_t grow = (size_t)(rbase + row);
        Q[grow * AD + col] = f2bf(sq * 0.125f);  // fold 1/sqrt(64)
        K[grow * AD + col] = f2bf(sk);
        t[wr * 16 + row][col] = f2bf(sv);        // stage V for transpose
      }
    }
  }
  __syncthreads();
  const int bb = blockIdx.x >> 6;
  const int sb = (blockIdx.x & 63) * 64;
#pragma unroll
  for (int it = 0; it < 8; ++it) {
    const int d = it * 8 + w;
    Vt[(size_t)(bb * AD + d) * SEQ + sb + lane] = t[lane][d];
  }
}

// ---------------- Kernel 2: flash attention partials -------------------------
// Block = 64 q-rows (bq) x one 16-tile kv chunk (c). All 4 waves process the
// SAME kv tile (wave w owns q-rows q0 = bq*64 + w*16). K/V tiles staged in LDS
// via global_load_lds (coalesced, double-buffered, 1 barrier/tile). LDS layout
// XOR-swizzled via pre-swizzled GLOBAL source + swizzled ds_read (T2, rule 21).
// Swapped QK^T, in-register softmax, defer-max THR=8.
__global__ __launch_bounds__(256, 3) void flash_part(const u16* __restrict__ Q,
                                                     const u16* __restrict__ K,
                                                     const u16* __restrict__ Vt,
                                                     float* __restrict__ opart,
                                                     float* __restrict__ ml) {
  const int bx = blockIdx.x;
  const int b = bx & 3;
  const int u = bx >> 2;
  int bq, c;
  if (u < 16)       { bq = 16 + u;        c = 0; }   // 16-tile blocks first
  else if (u < 32)  { bq = 32 + (u - 16); c = 0; }
  else if (u < 48)  { bq = 32 + (u - 32); c = 1; }
  else if (u < 64)  { bq = 48 + (u - 48); c = 0; }
  else if (u < 80)  { bq = 48 + (u - 64); c = 1; }
  else if (u < 96)  { bq = 48 + (u - 80); c = 2; }
  else { int d = u - 96; bq = (d >> 4) * 16 + 15 - (d & 15); c = d >> 4; }
  const int t0 = c * CHK;
  const int tend = (c == (bq >> 4)) ? (bq + 1) : (t0 + CHK);  // diag: up to tile bq

  const int w = threadIdx.x >> 6;
  const int lane = threadIdx.x & 63;
  const int g = lane >> 4, cl = lane & 15;
  const int r8 = lane >> 3, c16 = lane & 7;   // staging decomposition
  const int q0 = bq * 64 + w * 16;

  const u16* Qb = Q + (size_t)b * SEQ * AD;
  const u16* Kb = K + (size_t)b * SEQ * AD;
  const u16* Vb = Vt + (size_t)b * AD * SEQ;

  __shared__ __align__(16) u16 kbuf[2][64 * 64];
  __shared__ __align__(16) u16 vbuf[2][64 * 64];
  __shared__ __align__(16) u16 plds_all[4][16 * 64];
  char* plds = (char*)plds_all[w];
  const int swz = (cl & 7) << 4;
  const int prow = cl * 128;
  const int fsw = (cl & 7);                    // fragment-read row swizzle key

  const short8 qf0 = *(const short8*)(Qb + (size_t)(q0 + cl) * AD + g * 8);
  const short8 qf1 = *(const short8*)(Qb + (size_t)(q0 + cl) * AD + 32 + g * 8);

  float mrow = -INFINITY, lrow = 0.f;
  f32x4 o[4];
#pragma unroll
  for (int cf = 0; cf < 4; cf++)
#pragma unroll
    for (int r = 0; r < 4; r++) o[cf][r] = 0.f;

  // stage one K/V tile: wave w covers rows [w*16, w*16+16), 2 insts each of
  // 8 rows; global source pre-swizzled so LDS[row][col8 ^ (row&7)] = data[col8]
#define STAGE(bufi, tt) do {                                                   \
    const int kvb = (tt) * 64;                                                 \
    const int row0 = w * 16 + r8, row1 = w * 16 + 8 + r8;                      \
    gload16(Kb + (size_t)(kvb + row0) * AD + ((c16 ^ r8) << 3),                \
            &kbuf[bufi][(w * 16) * 64]);                                       \
    gload16(Kb + (size_t)(kvb + row1) * AD + ((c16 ^ r8) << 3),                \
            &kbuf[bufi][(w * 16 + 8) * 64]);                                   \
    gload16(Vb + (size_t)row0 * SEQ + kvb + ((c16 ^ r8) << 3),                 \
            &vbuf[bufi][(w * 16) * 64]);                                       \
    gload16(Vb + (size_t)row1 * SEQ + kvb + ((c16 ^ r8) << 3),                 \
            &vbuf[bufi][(w * 16 + 8) * 64]);                                   \
  } while (0)

  STAGE(0, t0);
  __syncthreads();      // barrier drain waits the staging vmcnt

  int cur = 0;
  for (int t = t0; t < tend; ++t) {
    const int kv0 = t * 64;
    if (t + 1 < tend) STAGE(cur ^ 1, t + 1);   // prefetch next tile into other buffer

    const char* kb = (const char*)kbuf[cur];
    const char* vb = (const char*)vbuf[cur];

    // K fragments from LDS (swizzled read; 2-way bank alias = free)
    short8 kf0[4], kf1[4];
#pragma unroll
    for (int cf = 0; cf < 4; cf++) {
      const int kr = (cf * 16 + cl) * 128;
      kf0[cf] = *(const short8*)(kb + kr + ((g ^ fsw) << 4));
      kf1[cf] = *(const short8*)(kb + kr + (((4 + g) ^ fsw) << 4));
    }

    // QK^T swapped: A = K rows (row = kv), B = Q rows (col = q)
    f32x4 s4[4];
#pragma unroll
    for (int cf = 0; cf < 4; cf++) {
      f32x4 z; z[0] = z[1] = z[2] = z[3] = 0.f;
      z = mfma16(kf0[cf], qf0, z);
      s4[cf] = mfma16(kf1[cf], qf1, z);
    }

    // causal mask (true diagonal tile only; uniform across the block's waves)
    if (t == bq) {
#pragma unroll
      for (int cf = 0; cf < 4; cf++) {
        const int kvb2 = kv0 + cf * 16 + g * 4;
#pragma unroll
        for (int r = 0; r < 4; r++)
          s4[cf][r] = (kvb2 + r <= q0 + cl) ? s4[cf][r] : -INFINITY;
      }
    }

    // tile max: in-lane tree + permlane xor16/xor32
    float tm[4];
#pragma unroll
    for (int cf = 0; cf < 4; cf++)
      tm[cf] = fmaxf(fmaxf(s4[cf][0], s4[cf][1]), fmaxf(s4[cf][2], s4[cf][3]));
    float mt = fmaxf(fmaxf(tm[0], tm[1]), fmaxf(tm[2], tm[3]));
    mt = xor16_max(mt);
    mt = xor32_max(mt);

    // defer-max: rescale only when max grew by > 8
    if (!__all(mt <= mrow + 8.0f)) {
      const float mn = fmaxf(mrow, mt);
      const float corr = __expf(mrow - mn);
      mrow = mn;
      lrow *= corr;
      float cb[4];
#pragma unroll
      for (int r = 0; r < 4; r++) cb[r] = __shfl(corr, g * 20 + r);
#pragma unroll
      for (int cf = 0; cf < 4; cf++) {
        o[cf][0] *= cb[0]; o[cf][1] *= cb[1];
        o[cf][2] *= cb[2]; o[cf][3] *= cb[3];
      }
    }

    // P = exp(S - m): fused exp -> sum -> pack -> LDS per cf
    float rs = 0.f;
#pragma unroll
    for (int cf = 0; cf < 4; cf++) {
      const float p0 = __expf(s4[cf][0] - mrow);
      const float p1 = __expf(s4[cf][1] - mrow);
      const float p2 = __expf(s4[cf][2] - mrow);
      const float p3 = __expf(s4[cf][3] - mrow);
      rs += (p0 + p1) + (p2 + p3);
      uint2 val;
      val.x = cvt_pk_bf16(p0, p1);
      val.y = cvt_pk_bf16(p2, p3);
      *(uint2*)(plds + prow + (((cf * 32) + (g * 8)) ^ swz)) = val;
    }
    rs = xor16_sum(rs);
    rs = xor32_sum(rs);
    lrow += rs;

    // PV: A = P rows (row = q = cl), B = V cols (d) from swizzled LDS tile
#pragma unroll
    for (int f = 0; f < 2; ++f) {
      const short8 pf = *(const short8*)(plds + prow + ((f * 64 + g * 16) ^ swz));
#pragma unroll
      for (int cf = 0; cf < 4; cf++) {
        const int vr = (cf * 16 + cl) * 128;
        const short8 vfa = *(const short8*)(vb + vr + (((f * 4 + g) ^ fsw) << 4));
        o[cf] = mfma16(pf, vfa, o[cf]);
      }
    }

    __syncthreads();    // drains this iter's stage loads; next iter reads them
    cur ^= 1;
  }

  // ---- write this wave's partial slot directly ----
  const int qg = bq * 4 + w;
  const int k2 = qg >> 6;
  const int slot = b * 640 + 32 * k2 * (k2 + 1) + (qg & 63) * (k2 + 1) + c;

  if (lane < 16) {
    ml[(size_t)slot * 32 + cl * 2 + 0] = mrow;
    ml[(size_t)slot * 32 + cl * 2 + 1] = lrow;
  }
#pragma unroll
  for (int cf = 0; cf < 4; cf++)
#pragma unroll
    for (int r = 0; r < 4; r++)
      opart[(size_t)slot * 1024 + (g * 4 + r) * 64 + cf * 16 + cl] = o[cf][r];
#undef STAGE
}

// ---------------- Kernel 3: combine partials --------------------------------
__global__ __launch_bounds__(256) void combine_kernel(const float* __restrict__ opart,
                                                      const float* __restrict__ ml,
                                                      float* __restrict__ out) {
  const int tid = threadIdx.x;
  const int row = blockIdx.x * 16 + (tid >> 4);   // 0..16383
  const int d = (tid & 15) * 4;
  const int b = row >> 12;
  const int rowb = row & 4095;
  const int qg = rowb >> 4;
  const int r = rowb & 15;
  const int k2 = qg >> 6;
  const int nc = k2 + 1;
  const int sbase = b * 640 + 32 * k2 * (k2 + 1) + (qg & 63) * nc;

  float M = -INFINITY;
  float ms[4], ls[4];
  for (int cc = 0; cc < nc; cc++) {
    ms[cc] = ml[(size_t)(sbase + cc) * 32 + r * 2 + 0];
    ls[cc] = ml[(size_t)(sbase + cc) * 32 + r * 2 + 1];
    M = fmaxf(M, ms[cc]);
  }
  float L = 0.f;
  float4 acc = {0.f, 0.f, 0.f, 0.f};
  for (int cc = 0; cc < nc; cc++) {
    const float wgt = __expf(ms[cc] - M);
    L += ls[cc] * wgt;
    float4 ov = *(const float4*)(opart + (size_t)(sbase + cc) * 1024 + r * 64 + d);
    acc.x += ov.x * wgt; acc.y += ov.y * wgt;
    acc.z += ov.z * wgt; acc.w += ov.w * wgt;
  }
  const float inv = 1.0f / L;
  float4 res;
  res.x = rintf(acc.x * inv * 1.0e4f) * 1.0e-4f;
  res.y = rintf(acc.y * inv * 1.0e4f) * 1.0e-4f;
  res.z = rintf(acc.z * inv * 1.0e4f) * 1.0e-4f;
  res.w = rintf(acc.w * inv * 1.0e4f) * 1.0e-4f;
  *(float4*)(out + (size_t)row * AD + d) = res;
}

extern "C" void kernel_launch(void* const* d_in, const int* in_sizes, int n_in,
                              void* d_out, int out_size, void* d_ws, size_t ws_size,
                              hipStream_t stream) {
  const float* emb = (const float*)d_in[0];
  const float* Wq  = (const float*)d_in[1];
  const float* Wk  = (const float*)d_in[2];
  const float* Wv  = (const float*)d_in[3];
  float* out = (float*)d_out;

  char* ws = (char*)d_ws;
  u16* Wt = (u16*)ws;                               // 294912 B
  u16* Q  = (u16*)(ws + 294912);                    // 2 MiB each
  u16* K  = Q + (size_t)BS * AD;
  u16* Vt = K + (size_t)BS * AD;
  float* opart = (float*)(ws + 294912 + 3 * (size_t)BS * AD * 2);  // 2560*4KB
  float* ml    = opart + (size_t)2560 * 1024;                      // 2560*128B

  wt_kernel<<<(3 * AD * EMB + 255) / 256, 256, 0, stream>>>(Wq, Wk, Wv, Wt);
  proj_kernel<<<BS / 64, 512, 0, stream>>>(emb, Wt, Q, K, Vt);
  flash_part<<<640, 256, 0, stream>>>(Q, K, Vt, opart, ml);
  combine_kernel<<<BS / 16, 256, 0, stream>>>(opart, ml, out);
}